// Round 9
// baseline (1580.542 us; speedup 1.0000x reference)
//
#include <hip/hip_runtime.h>
#include <hip/hip_bf16.h>
#include <math.h>

typedef __hip_bfloat16 bf16;
typedef unsigned short u16;
typedef __attribute__((ext_vector_type(8))) short short8;   // 8 bf16 (4 VGPRs)
typedef __attribute__((ext_vector_type(4))) float f32x4;

__device__ __forceinline__ float LD(const float* p) { return *p; }
__device__ __forceinline__ float LD(const bf16* p)  { return __bfloat162float(*p); }
__device__ __forceinline__ void  ST(float* p, float v) { *p = v; }
__device__ __forceinline__ void  ST(bf16* p, float v)  { *p = __float2bfloat16(v); }
__device__ __forceinline__ u16   f2b(float v) { bf16 h = __float2bfloat16(v); return *reinterpret_cast<u16*>(&h); }
__device__ __forceinline__ float b2fu(u16 u) { bf16 h = *reinterpret_cast<bf16*>(&u); return __bfloat162float(h); }

// ---------------- f32 copy ----------------
__global__ __launch_bounds__(256) void copy_kernel(const float* __restrict__ in,
                                                   float* __restrict__ out, int n) {
    int i = blockIdx.x * blockDim.x + threadIdx.x;
    if (i < n) out[i] = in[i];
}

// ---- NCHW f32 -> NHWC f32 (LDS-tiled transpose) ----
__global__ __launch_bounds__(256) void nhwc_f32_kernel(const float* __restrict__ in,
                                                       float* __restrict__ out,
                                                       int C, int HW)
{
    __shared__ float tile[32][65];
    const int b = blockIdx.z;
    const int c0 = blockIdx.y * 32;
    const int p0 = blockIdx.x * 64;
    for (int i = threadIdx.x; i < 2048; i += 256) {
        const int c_ = i >> 6, p_ = i & 63;
        tile[c_][p_] = in[((size_t)(b * C + c0 + c_)) * HW + p0 + p_];
    }
    __syncthreads();
    for (int i = threadIdx.x; i < 2048; i += 256) {
        const int p_ = i >> 5, c_ = i & 31;
        out[((size_t)b * HW + p0 + p_) * C + c0 + c_] = tile[c_][p_];
    }
}

// ---- wsplit (layout [t][o][c], for off-convs) ----
__global__ __launch_bounds__(256) void wsplit_kernel(const float* __restrict__ w,
                                                     u16* __restrict__ hi, u16* __restrict__ lo,
                                                     int O, int C, int KK)
{
    const int i = blockIdx.x * 256 + threadIdx.x;
    const int n = O * C * KK;
    if (i >= n) return;
    const int o = i / (C * KK);
    const int r = i - o * C * KK;
    const int c = r / KK;
    const int t = r - c * KK;
    const float v = w[i];
    const bf16 h = __float2bfloat16(v);
    const float hv = __bfloat162float(h);
    const bf16 l = __float2bfloat16(v - hv);
    const size_t dst = ((size_t)t * O + o) * C + c;
    hi[dst] = *(const u16*)&h;
    lo[dst] = *(const u16*)&l;
}

// ---- wsplit2: layout [t][cc][quad][O][8] for conv_mfma3 + mdcn_mfma ----
__global__ __launch_bounds__(256) void wsplit2_kernel(const float* __restrict__ w,
                                                      u16* __restrict__ hi, u16* __restrict__ lo,
                                                      int O, int C, int KK)
{
    const int i = blockIdx.x * 256 + threadIdx.x;
    const int n = O * C * KK;
    if (i >= n) return;
    const int o = i / (C * KK);
    const int r = i - o * C * KK;
    const int c = r / KK;
    const int t = r - c * KK;
    const float v = w[i];
    const bf16 h = __float2bfloat16(v);
    const float hv = __bfloat162float(h);
    const bf16 l = __float2bfloat16(v - hv);
    const int nch = C >> 5;
    const int cc = c >> 5, quad = (c >> 3) & 3, q = c & 7;
    const size_t dst = ((((size_t)t * nch + cc) * 4 + quad) * O + o) * 8 + q;
    hi[dst] = *(const u16*)&h;
    lo[dst] = *(const u16*)&l;
}

// ---- wsplit2p: like wsplit2 but zero-padded output channels to OP (conv6: O=3 -> OP=32) ----
__global__ __launch_bounds__(256) void wsplit2p_kernel(const float* __restrict__ w,
                                                       u16* __restrict__ hi, u16* __restrict__ lo,
                                                       int O, int OP, int C, int KK)
{
    const int i = blockIdx.x * 256 + threadIdx.x;
    const int n = OP * C * KK;
    if (i >= n) return;
    const int o = i / (C * KK);
    const int r = i - o * C * KK;
    const int c = r / KK;
    const int t = r - c * KK;
    float v = 0.f;
    if (o < O) v = w[((size_t)o * C + c) * KK + t];
    const bf16 h = __float2bfloat16(v);
    const float hv = __bfloat162float(h);
    const bf16 l = __float2bfloat16(v - hv);
    const int nch = C >> 5;
    const int cc = c >> 5, quad = (c >> 3) & 3, q = c & 7;
    const size_t dst = ((((size_t)t * nch + cc) * 4 + quad) * OP + o) * 8 + q;
    hi[dst] = *(const u16*)&h;
    lo[dst] = *(const u16*)&l;
}

// ---- wsplitL: row-lumped subpixel weights for conv_mfma5 (UP 5x5 -> 15 taps) ----
__global__ __launch_bounds__(256) void wsplitL_kernel(const float* __restrict__ w,
        u16* __restrict__ lh, u16* __restrict__ ll, u16* __restrict__ ch, int O, int C)
{
    const int i = blockIdx.x * 256 + threadIdx.x;
    const int n = O * C * 50;
    if (i >= n) return;
    const int s = i / (O * C);
    const int r = i - s * (O * C);
    const int o = r / C;
    const int c = r - o * C;
    const size_t U = (size_t)C * O;
    const int cc = c >> 5, quad = (c >> 3) & 3, q = c & 7;
    const size_t din = (((size_t)cc * 4 + quad) * O + o) * 8 + q;
    const float* wp = w + ((size_t)o * C + c) * 25;
    if (s < 30) {
        const int ry = s / 15, rem = s % 15, j = rem / 5, tx = rem % 5;
        int ys, yn;
        if (ry == 0) { ys = (j == 0) ? 0 : (j == 1) ? 2 : 4; yn = (j == 2) ? 1 : 2; }
        else         { ys = (j == 0) ? 0 : (j == 1) ? 1 : 3; yn = (j == 0) ? 1 : 2; }
        float v = 0.f;
        for (int ty = ys; ty < ys + yn; ++ty) v += wp[ty * 5 + tx];
        const bf16 h = __float2bfloat16(v);
        const bf16 l = __float2bfloat16(v - __bfloat162float(h));
        lh[(size_t)s * U + din] = *(const u16*)&h;
        ll[(size_t)s * U + din] = *(const u16*)&l;
    } else {
        const int t = s - 30;
        const int cidx = t / 5, tx = t - cidx * 5;
        const int tyc = (cidx == 0) ? 0 : (cidx == 1) ? 1 : (cidx == 2) ? 3 : 4;
        const bf16 h = __float2bfloat16(wp[tyc * 5 + tx]);
        ch[(size_t)t * U + din] = *(const u16*)&h;
    }
}

// ======== conv_mfma3: tiled-input MFMA conv, B direct from global (REFLECT pad) ========
template<typename T1, typename T2, int K, bool UP, int EPI, bool ASPLIT,
         int NR, int NCOL, int MT, int MW, bool XPIN>
__global__ __launch_bounds__(MW * 128) void conv_mfma3(
        const T1* __restrict__ src1, const T2* __restrict__ src2,
        int C1, int C,
        const u16* __restrict__ wth, const u16* __restrict__ wtl,
        const float* __restrict__ bias,
        void* __restrict__ outv, int O, int H, int W)
{
    constexpr int KK = K * K;
    constexpr int ATILE = NR * NCOL * 32;
    __shared__ __align__(16) u16 Ah[ATILE];
    __shared__ __align__(16) u16 Al[ASPLIT ? ATILE : 8];

    const int tid  = threadIdx.x;
    const int lane = tid & 63;
    const int wv   = tid >> 6;
    const int ln15 = lane & 15;
    const int quad = lane >> 4;
    const int mi = wv % MW, ni = wv / MW;
    int b, p0;
    if (XPIN) {
        const int flat = blockIdx.x + gridDim.x * blockIdx.y;
        b = flat & 7;
        p0 = (flat >> 3) * (MT * 16 * MW);
    } else {
        b = blockIdx.y;
        p0 = blockIdx.x * (MT * 16 * MW);
    }
    const int obase = blockIdx.z * 64;
    const int HW = H * W;
    const int SH = UP ? (H >> 1) : H;
    const int SW = UP ? (W >> 1) : W;
    const int SHW = SH * SW;
    const int PAD = K / 2;
    const int C2 = C - C1;
    const int nch = C >> 5;

    const int y0 = p0 / W;
    const int rbase = (y0 <= PAD) ? 0 : (UP ? ((y0 - PAD) >> 1) : (y0 - PAD));

    int rs[MT][K], cs[MT][K];
#pragma unroll
    for (int ms = 0; ms < MT; ++ms) {
        const int pm = p0 + mi * (MT * 16) + ms * 16 + ln15;
        const int ym = pm / W, xm = pm - ym * W;
#pragma unroll
        for (int tt = 0; tt < K; ++tt) {
            int yy = ym + tt - PAD;
            yy = yy < 0 ? -yy : yy; yy = yy >= H ? 2 * H - 2 - yy : yy;
            rs[ms][tt] = (UP ? (yy >> 1) : yy) - rbase;
            int xx = xm + tt - PAD;
            xx = xx < 0 ? -xx : xx; xx = xx >= W ? 2 * W - 2 - xx : xx;
            cs[ms][tt] = UP ? (xx >> 1) : xx;
        }
    }

    f32x4 acc[MT][2];
#pragma unroll
    for (int i = 0; i < MT; ++i)
#pragma unroll
        for (int j = 0; j < 2; ++j) acc[i][j] = (f32x4)0.f;

    for (int cc = 0; cc < nch; ++cc) {
        const int c0 = cc << 5;
        __syncthreads();
        for (int idx = tid; idx < NR * NCOL * 4; idx += MW * 128) {
            const int c_ = idx % NCOL;
            const int r_ = (idx / NCOL) % NR;
            const int cq = idx / (NCOL * NR);
            int rr = rbase + r_; rr = rr >= SH ? SH - 1 : rr;
            const int sidx = rr * SW + c_;
            short8 vh, vl;
#pragma unroll
            for (int q = 0; q < 8; ++q) {
                const int c = c0 + cq * 8 + q;
                float v;
                if (c < C1) v = LD(src1 + (size_t)(b * C1 + c) * SHW + sidx);
                else        v = LD(src2 + (size_t)(b * C2 + (c - C1)) * SHW + sidx);
                const u16 hv = f2b(v);
                vh[q] = (short)hv;
                if (ASPLIT) vl[q] = (short)f2b(v - b2fu(hv));
            }
            *(short8*)&Ah[idx * 8] = vh;
            if (ASPLIT) *(short8*)&Al[idx * 8] = vl;
        }
        __syncthreads();

#pragma unroll
        for (int t = 0; t < KK; ++t) {
            const int ty = t / K, tx = t - ty * K;
            const size_t wb0 = ((((size_t)t * nch + cc) * 4 + quad) * O
                                + obase + ni * 32 + ln15) * 8;
            const short8 b0h = *(const short8*)(wth + wb0);
            const short8 b1h = *(const short8*)(wth + wb0 + 128);
            const short8 b0l = *(const short8*)(wtl + wb0);
            const short8 b1l = *(const short8*)(wtl + wb0 + 128);
#pragma unroll
            for (int ms = 0; ms < MT; ++ms) {
                const int ao = ((quad * NR + rs[ms][ty]) * NCOL + cs[ms][tx]) * 8;
                const short8 a = *(const short8*)&Ah[ao];
                acc[ms][0] = __builtin_amdgcn_mfma_f32_16x16x32_bf16(a, b0h, acc[ms][0], 0, 0, 0);
                acc[ms][0] = __builtin_amdgcn_mfma_f32_16x16x32_bf16(a, b0l, acc[ms][0], 0, 0, 0);
                acc[ms][1] = __builtin_amdgcn_mfma_f32_16x16x32_bf16(a, b1h, acc[ms][1], 0, 0, 0);
                acc[ms][1] = __builtin_amdgcn_mfma_f32_16x16x32_bf16(a, b1l, acc[ms][1], 0, 0, 0);
                if (ASPLIT) {
                    const short8 al = *(const short8*)&Al[ao];
                    acc[ms][0] = __builtin_amdgcn_mfma_f32_16x16x32_bf16(al, b0h, acc[ms][0], 0, 0, 0);
                    acc[ms][1] = __builtin_amdgcn_mfma_f32_16x16x32_bf16(al, b1h, acc[ms][1], 0, 0, 0);
                }
            }
        }
    }

#pragma unroll
    for (int ms = 0; ms < MT; ++ms) {
#pragma unroll
        for (int ns = 0; ns < 2; ++ns) {
            const int o = obase + ni * 32 + ns * 16 + ln15;
            const float bv = (EPI == 3) ? (o < 3 ? bias[o] : 0.f) : bias[o];
            const f32x4 av = acc[ms][ns];
#pragma unroll
            for (int r = 0; r < 4; ++r) {
                const int pp = p0 + mi * (MT * 16) + ms * 16 + (quad << 2) + r;
                const float v = av[r] + bv;
                if (EPI == 0) {
                    ((float*)outv)[((size_t)(b * O + o)) * HW + pp] = v;
                } else if (EPI == 3) {
                    if (o < 3)
                        ((float*)outv)[((size_t)(b * 3 + o)) * HW + pp] = tanhf(v);
                } else {
                    ((bf16*)outv)[((size_t)(b * O + o)) * HW + pp] = __float2bfloat16(v);
                }
            }
        }
    }
}

// ======== conv_mfma5: row-lumped UP 5x5 conv (15 taps) with exact border corr ========
template<typename T1, typename T2, int NR, int NCOL, int MT, int MW>
__global__ __launch_bounds__(MW * 128) void conv_mfma5(
        const T1* __restrict__ src1, const T2* __restrict__ src2,
        int C1, int C,
        const u16* __restrict__ wLh, const u16* __restrict__ wLl,
        const u16* __restrict__ wCh,
        const float* __restrict__ bias,
        bf16* __restrict__ out, int O, int H, int W)
{
    constexpr int NRR = NR + 1;
    __shared__ __align__(16) u16 Ah[4 * NRR * NCOL * 8];

    const int tid  = threadIdx.x;
    const int lane = tid & 63;
    const int wv   = tid >> 6;
    const int ln15 = lane & 15;
    const int quad = lane >> 4;
    const int mi = wv % MW, ni = wv / MW;
    const int b = blockIdx.y;
    const int p0 = blockIdx.x * (MT * 16 * MW);
    const int obase = blockIdx.z * 64;
    const int HW = H * W;
    const int SH = H >> 1, SW = W >> 1;
    const int SHW = SH * SW;
    const int C2 = C - C1;
    const int nch = C >> 5;
    const size_t U = (size_t)C * O;

    const int y0 = p0 / W;
    const int rbase = (y0 <= 2) ? 0 : ((y0 - 2) >> 1);

    const int ym0 = (p0 + mi * (MT * 16)) / W;
    const int ry = ym0 & 1;
    const int uu = ym0 >> 1;
    int r0 = uu - 1, r2 = uu + 1;
    r0 = r0 < 0 ? 1 : r0;
    r2 = r2 >= SH ? SH - 2 : r2;
    const int rg0 = r0 - rbase, rg1 = uu - rbase, rg2 = r2 - rbase;

    const bool isTopW = (ym0 <= 1), isBotW = (ym0 >= H - 2);
    const bool isBorderW = isTopW || isBotW;
    int cidx = 0;
    if (isTopW) cidx = (ym0 == 0) ? 1 : 0;
    if (isBotW) cidx = (ym0 == H - 2) ? 3 : 2;
    const bool blkTop = (p0 == 0);
    const bool blkBot = (p0 + MW * MT * 16 == HW);
    const bool blkEdge = blkTop || blkBot;

    int cs[MT][5];
#pragma unroll
    for (int ms = 0; ms < MT; ++ms) {
        const int pm = p0 + mi * (MT * 16) + ms * 16 + ln15;
        const int xm = pm % W;
#pragma unroll
        for (int tt = 0; tt < 5; ++tt) {
            int xx = xm + tt - 2;
            xx = xx < 0 ? -xx : xx; xx = xx >= W ? 2 * W - 2 - xx : xx;
            cs[ms][tt] = xx >> 1;
        }
    }

    f32x4 acc[MT][2];
#pragma unroll
    for (int i = 0; i < MT; ++i)
#pragma unroll
        for (int j = 0; j < 2; ++j) acc[i][j] = (f32x4)0.f;

    for (int cc = 0; cc < nch; ++cc) {
        const int c0 = cc << 5;
        __syncthreads();
        for (int idx = tid; idx < NR * NCOL * 4; idx += MW * 128) {
            const int c_ = idx % NCOL;
            const int r_ = (idx / NCOL) % NR;
            const int cq = idx / (NCOL * NR);
            int rr = rbase + r_; rr = rr >= SH ? SH - 1 : rr;
            const int sidx = rr * SW + c_;
            short8 vh;
#pragma unroll
            for (int q = 0; q < 8; ++q) {
                const int c = c0 + cq * 8 + q;
                float v;
                if (c < C1) v = LD(src1 + (size_t)(b * C1 + c) * SHW + sidx);
                else        v = LD(src2 + (size_t)(b * C2 + (c - C1)) * SHW + sidx);
                vh[q] = (short)f2b(v);
            }
            *(short8*)&Ah[((cq * NRR + r_) * NCOL + c_) * 8] = vh;
        }
        if (blkEdge) {
            const int ra = blkTop ? 0 : SH - 1;
            const int rb2 = blkTop ? 1 : SH - 2;
            for (int idx = tid; idx < NCOL * 4; idx += MW * 128) {
                const int c_ = idx % NCOL;
                const int cq = idx / NCOL;
                short8 vh;
#pragma unroll
                for (int q = 0; q < 8; ++q) {
                    const int c = c0 + cq * 8 + q;
                    float va, vb;
                    if (c < C1) {
                        const size_t base = (size_t)(b * C1 + c) * SHW;
                        va = LD(src1 + base + ra * SW + c_);
                        vb = LD(src1 + base + rb2 * SW + c_);
                    } else {
                        const size_t base = (size_t)(b * C2 + (c - C1)) * SHW;
                        va = LD(src2 + base + ra * SW + c_);
                        vb = LD(src2 + base + rb2 * SW + c_);
                    }
                    vh[q] = (short)f2b(va - vb);
                }
                *(short8*)&Ah[((cq * NRR + NR) * NCOL + c_) * 8] = vh;
            }
        }
        __syncthreads();

        const size_t wq = ((size_t)(cc * 4 + quad) * O + obase + ni * 32 + ln15) * 8;
#pragma unroll
        for (int j = 0; j < 3; ++j) {
            const int rgj = (j == 0) ? rg0 : (j == 1) ? rg1 : rg2;
#pragma unroll
            for (int tx = 0; tx < 5; ++tx) {
                const size_t wb = (size_t)((ry * 3 + j) * 5 + tx) * U + wq;
                const short8 b0h = *(const short8*)(wLh + wb);
                const short8 b1h = *(const short8*)(wLh + wb + 128);
                const short8 b0l = *(const short8*)(wLl + wb);
                const short8 b1l = *(const short8*)(wLl + wb + 128);
#pragma unroll
                for (int ms = 0; ms < MT; ++ms) {
                    const int ao = ((quad * NRR + rgj) * NCOL + cs[ms][tx]) * 8;
                    const short8 a = *(const short8*)&Ah[ao];
                    acc[ms][0] = __builtin_amdgcn_mfma_f32_16x16x32_bf16(a, b0h, acc[ms][0], 0, 0, 0);
                    acc[ms][0] = __builtin_amdgcn_mfma_f32_16x16x32_bf16(a, b0l, acc[ms][0], 0, 0, 0);
                    acc[ms][1] = __builtin_amdgcn_mfma_f32_16x16x32_bf16(a, b1h, acc[ms][1], 0, 0, 0);
                    acc[ms][1] = __builtin_amdgcn_mfma_f32_16x16x32_bf16(a, b1l, acc[ms][1], 0, 0, 0);
                }
            }
        }
        if (isBorderW) {
#pragma unroll
            for (int tx = 0; tx < 5; ++tx) {
                const size_t wb = (size_t)(cidx * 5 + tx) * U + wq;
                const short8 b0 = *(const short8*)(wCh + wb);
                const short8 b1 = *(const short8*)(wCh + wb + 128);
#pragma unroll
                for (int ms = 0; ms < MT; ++ms) {
                    const int ao = ((quad * NRR + NR) * NCOL + cs[ms][tx]) * 8;
                    const short8 a = *(const short8*)&Ah[ao];
                    acc[ms][0] = __builtin_amdgcn_mfma_f32_16x16x32_bf16(a, b0, acc[ms][0], 0, 0, 0);
                    acc[ms][1] = __builtin_amdgcn_mfma_f32_16x16x32_bf16(a, b1, acc[ms][1], 0, 0, 0);
                }
            }
        }
    }

#pragma unroll
    for (int ms = 0; ms < MT; ++ms) {
#pragma unroll
        for (int ns = 0; ns < 2; ++ns) {
            const int o = obase + ni * 32 + ns * 16 + ln15;
            const float bv = bias[o];
            const f32x4 av = acc[ms][ns];
#pragma unroll
            for (int r = 0; r < 4; ++r) {
                const int pp = p0 + mi * (MT * 16) + ms * 16 + (quad << 2) + r;
                out[((size_t)(b * O + o)) * HW + pp] = __float2bfloat16(av[r] + bv);
            }
        }
    }
}

// ---- bilinear param helper (shared by mdcn) ----
__device__ __forceinline__ void bil_params(float py, float pxx, float mk, int H, int W,
                                           float* w4, int* i4)
{
    const float y0f = floorf(py), x0f = floorf(pxx);
    const int y0 = (int)y0f, x0 = (int)x0f;
    const float wy1 = py - y0f, wx1 = pxx - x0f;
    const float wy0 = 1.f - wy1, wx0 = 1.f - wx1;
    const bool r0v = (y0 >= 0 && y0 < H), r1v = (y0 + 1 >= 0 && y0 + 1 < H);
    const bool c0v = (x0 >= 0 && x0 < W), c1v = (x0 + 1 >= 0 && x0 + 1 < W);
    w4[0] = (r0v && c0v) ? wy0 * wx0 * mk : 0.f;
    w4[1] = (r0v && c1v) ? wy0 * wx1 * mk : 0.f;
    w4[2] = (r1v && c0v) ? wy1 * wx0 * mk : 0.f;
    w4[3] = (r1v && c1v) ? wy1 * wx1 * mk : 0.f;
    i4[0] = (r0v ? y0 : 0) * W + (c0v ? x0 : 0);
    i4[1] = (r0v ? y0 : 0) * W + (c1v ? x0 + 1 : 0);
    i4[2] = (r1v ? y0 + 1 : 0) * W + (c0v ? x0 : 0);
    i4[3] = (r1v ? y0 + 1 : 0) * W + (c1v ? x0 + 1 : 0);
}

// ---- per-thread gather+pack of one A fragment (8 ch of one pixel, f32 NHWC) ----
template<bool ASPLIT>
__device__ __forceinline__ void gather_frag(const float* __restrict__ xb, const float* w4,
                                            const int* i4, int C, int cbase,
                                            short8& vh, short8& vl)
{
    const float* p0 = xb + (size_t)i4[0] * C + cbase;
    const float* p1 = xb + (size_t)i4[1] * C + cbase;
    const float* p2 = xb + (size_t)i4[2] * C + cbase;
    const float* p3 = xb + (size_t)i4[3] * C + cbase;
    const f32x4 a0 = *(const f32x4*)p0, b0 = *(const f32x4*)(p0 + 4);
    const f32x4 a1 = *(const f32x4*)p1, b1 = *(const f32x4*)(p1 + 4);
    const f32x4 a2 = *(const f32x4*)p2, b2 = *(const f32x4*)(p2 + 4);
    const f32x4 a3 = *(const f32x4*)p3, b3 = *(const f32x4*)(p3 + 4);
#pragma unroll
    for (int q = 0; q < 4; ++q) {
        const float v = w4[0] * a0[q] + w4[1] * a1[q] + w4[2] * a2[q] + w4[3] * a3[q];
        const u16 hv = f2b(v);
        vh[q] = (short)hv;
        if (ASPLIT) vl[q] = (short)f2b(v - b2fu(hv));
    }
#pragma unroll
    for (int q = 0; q < 4; ++q) {
        const float v = w4[0] * b0[q] + w4[1] * b1[q] + w4[2] * b2[q] + w4[3] * b3[q];
        const u16 hv = f2b(v);
        vh[4 + q] = (short)hv;
        if (ASPLIT) vl[4 + q] = (short)f2b(v - b2fu(hv));
    }
}

// ========== mdcn_mfma: deformable conv, BARRIER-FREE register-direct fragments ==========
// XCD-pinned (b = flat&7). Each thread gathers its OWN MFMA A-fragment (pixel = m-row
// ln15 (+16), channels quad*8..+8, f32 NHWC) and loads its B-fragment straight from the
// wsplit2 layout — no LDS staging for A/B, zero in-loop barriers. 2x A-gather redundancy
// across ni waves (L1/L2-hot) traded for free compiler pipelining across chunks.
template<typename OT, bool ASPLIT>
__global__ __launch_bounds__(256) void mdcn_mfma(
        const float* __restrict__ skipf,
        const float* __restrict__ om,
        const u16* __restrict__ wth, const u16* __restrict__ wtl,
        const float* __restrict__ bias,
        OT* __restrict__ out, int C, int O, int H, int W)
{
    __shared__ float tpy[576], tpxs[576], tms[576];

    const int tid = threadIdx.x;
    const int lane = tid & 63;
    const int wv = tid >> 6;
    const int ln15 = lane & 15;
    const int quad = lane >> 4;
    const int mi = wv & 1, ni = wv >> 1;
    const int flat = blockIdx.x + gridDim.x * (blockIdx.y + 8 * blockIdx.z);
    const int b = flat & 7;
    const int rest = flat >> 3;
    const int p0 = (rest % gridDim.x) * 64;
    const int obase = (rest / gridDim.x) * 64;
    const int HW = H * W;
    const int nch = C >> 5;

    const float* omb = om + (size_t)b * 27 * HW;
    for (int i = tid; i < 576; i += 256) {
        const int k = i >> 6, px_ = i & 63;
        const int p = p0 + px_;
        const int y = p / W, x = p - y * W;
        const float dy = omb[(2 * k) * HW + p];
        const float dx = omb[(2 * k + 1) * HW + p];
        const float mk = 1.f / (1.f + expf(-omb[(18 + k) * HW + p]));
        float py = (float)(y + k / 3 - 1) + dy;
        float pxx = (float)(x + k % 3 - 1) + dx;
        py  = fminf(fmaxf(py, -2.f), (float)H + 1.f);
        pxx = fminf(fmaxf(pxx, -2.f), (float)W + 1.f);
        tpy[i] = py; tpxs[i] = pxx; tms[i] = mk;
    }
    __syncthreads();

    f32x4 acc[2][2];
#pragma unroll
    for (int i = 0; i < 2; ++i)
#pragma unroll
        for (int j = 0; j < 2; ++j) acc[i][j] = (f32x4)0.f;

    const float* xb = skipf + (size_t)b * HW * C;
    const int pixA = mi * 32 + ln15;
    const int pixB = pixA + 16;

    for (int k = 0; k < 9; ++k) {
        float wA[4], wB[4];
        int iA[4], iB[4];
        bil_params(tpy[k * 64 + pixA], tpxs[k * 64 + pixA], tms[k * 64 + pixA], H, W, wA, iA);
        bil_params(tpy[k * 64 + pixB], tpxs[k * 64 + pixB], tms[k * 64 + pixB], H, W, wB, iB);
        for (int cc = 0; cc < nch; ++cc) {
            const int cbase = (cc << 5) + (quad << 3);
            short8 a0h, a0l, a1h, a1l;
            gather_frag<ASPLIT>(xb, wA, iA, C, cbase, a0h, a0l);
            gather_frag<ASPLIT>(xb, wB, iB, C, cbase, a1h, a1l);
            const size_t base = ((((size_t)k * nch + cc) * 4 + quad) * O
                                 + obase + ni * 32 + ln15) * 8;
            const short8 b0h = *(const short8*)(wth + base);
            const short8 b1h = *(const short8*)(wth + base + 128);
            const short8 b0l = *(const short8*)(wtl + base);
            const short8 b1l = *(const short8*)(wtl + base + 128);
            acc[0][0] = __builtin_amdgcn_mfma_f32_16x16x32_bf16(a0h, b0h, acc[0][0], 0, 0, 0);
            acc[0][0] = __builtin_amdgcn_mfma_f32_16x16x32_bf16(a0h, b0l, acc[0][0], 0, 0, 0);
            acc[0][1] = __builtin_amdgcn_mfma_f32_16x16x32_bf16(a0h, b1h, acc[0][1], 0, 0, 0);
            acc[0][1] = __builtin_amdgcn_mfma_f32_16x16x32_bf16(a0h, b1l, acc[0][1], 0, 0, 0);
            acc[1][0] = __builtin_amdgcn_mfma_f32_16x16x32_bf16(a1h, b0h, acc[1][0], 0, 0, 0);
            acc[1][0] = __builtin_amdgcn_mfma_f32_16x16x32_bf16(a1h, b0l, acc[1][0], 0, 0, 0);
            acc[1][1] = __builtin_amdgcn_mfma_f32_16x16x32_bf16(a1h, b1h, acc[1][1], 0, 0, 0);
            acc[1][1] = __builtin_amdgcn_mfma_f32_16x16x32_bf16(a1h, b1l, acc[1][1], 0, 0, 0);
            if (ASPLIT) {
                acc[0][0] = __builtin_amdgcn_mfma_f32_16x16x32_bf16(a0l, b0h, acc[0][0], 0, 0, 0);
                acc[0][1] = __builtin_amdgcn_mfma_f32_16x16x32_bf16(a0l, b1h, acc[0][1], 0, 0, 0);
                acc[1][0] = __builtin_amdgcn_mfma_f32_16x16x32_bf16(a1l, b0h, acc[1][0], 0, 0, 0);
                acc[1][1] = __builtin_amdgcn_mfma_f32_16x16x32_bf16(a1l, b1h, acc[1][1], 0, 0, 0);
            }
        }
    }

#pragma unroll
    for (int ms = 0; ms < 2; ++ms) {
#pragma unroll
        for (int ns = 0; ns < 2; ++ns) {
            const int o = obase + ni * 32 + ns * 16 + ln15;
            const float bv = bias[o];
#pragma unroll
            for (int r = 0; r < 4; ++r) {
                const int pp = p0 + mi * 32 + ms * 16 + (quad << 2) + r;
                ST(out + ((size_t)(b * O + o)) * HW + pp, acc[ms][ns][r] + bv);
            }
        }
    }
}

// ================= conv_mfma — off-convs, XCD-pinned by batch =================
template<typename T1, typename T2, int K, bool REFLECT, bool UP, int NTN, int EPI, bool ASPLIT>
__global__ __launch_bounds__(256) void conv_mfma(
        const T1* __restrict__ src1, const T2* __restrict__ src2,
        int C1, int C,
        const u16* __restrict__ wth, const u16* __restrict__ wtl,
        const float* __restrict__ bias,
        void* __restrict__ outv, int O, int H, int W)
{
    constexpr int KK = K * K;
    __shared__ __align__(16) u16 As[64 * 40];
    __shared__ __align__(16) u16 Alo[ASPLIT ? 64 * 40 : 8];
    __shared__ __align__(16) u16 Bh[NTN * 16 * 40];
    __shared__ __align__(16) u16 Bl[NTN * 16 * 40];

    const int tid  = threadIdx.x;
    const int wv   = tid >> 6;
    const int lane = tid & 63;
    const int ln15 = lane & 15;
    const int flat = blockIdx.x + gridDim.x * blockIdx.y;
    const int b    = flat & 7;
    const int p0   = (flat >> 3) * 64;
    const int obase = blockIdx.z * (NTN * 16);
    const int HW = H * W;
    const int Hs = UP ? (H >> 1) : H;
    const int Ws = UP ? (W >> 1) : W;
    const int HsWs = Hs * Ws;
    const int PAD = K / 2;
    const int C2 = C - C1;
    const int m_stage = tid & 63;

    const int p = p0 + m_stage;
    const int y = p / W, x = p - y * W;
    int off[KK];
    float msk[KK];
#pragma unroll
    for (int ty = 0; ty < K; ++ty) {
#pragma unroll
        for (int tx = 0; tx < K; ++tx) {
            int yy = y + ty - PAD, xx = x + tx - PAD;
            bool vv = true;
            if (REFLECT) {
                yy = yy < 0 ? -yy : yy; yy = yy >= H ? 2 * H - 2 - yy : yy;
                xx = xx < 0 ? -xx : xx; xx = xx >= W ? 2 * W - 2 - xx : xx;
            } else {
                vv = (yy >= 0 && yy < H && xx >= 0 && xx < W);
                yy = yy < 0 ? 0 : (yy >= H ? H - 1 : yy);
                xx = xx < 0 ? 0 : (xx >= W ? W - 1 : xx);
            }
            off[ty * K + tx] = (UP ? (yy >> 1) : yy) * Ws + (UP ? (xx >> 1) : xx);
            msk[ty * K + tx] = vv ? 1.f : 0.f;
        }
    }

    f32x4 acc[NTN];
#pragma unroll
    for (int nt = 0; nt < NTN; ++nt) acc[nt] = (f32x4)0.f;

    const int aswz = (m_stage >> 3) & 3;
    const int awr  = m_stage * 40 + ((wv ^ aswz) << 3);
    const int arow = wv * 16 + ln15;
    const int ard  = arow * 40 + (((lane >> 4) ^ ((arow >> 3) & 3)) << 3);

    const int nch = C >> 5;
    for (int cc = 0; cc < nch; ++cc) {
        const int c0 = cc << 5;
        for (int t = 0; t < KK; ++t) {
            const int offt = off[t];
            const float mskt = msk[t];
            __syncthreads();
            {
                short8 avh, avl;
#pragma unroll
                for (int q = 0; q < 8; ++q) {
                    const int c = c0 + (wv << 3) + q;
                    float v;
                    if (c < C1) v = LD(src1 + ((size_t)(b * C1 + c)) * HsWs + offt);
                    else        v = LD(src2 + ((size_t)(b * C2 + (c - C1))) * HsWs + offt);
                    if (!REFLECT) v *= mskt;
                    const u16 hv = f2b(v);
                    avh[q] = (short)hv;
                    if (ASPLIT) avl[q] = (short)f2b(v - b2fu(hv));
                }
                *(short8*)&As[awr] = avh;
                if (ASPLIT) *(short8*)&Alo[awr] = avl;
            }
            for (int i = tid; i < NTN * 16 * 4; i += 256) {
                const int row = i >> 2, part = i & 3;
                int o = obase + row; if (o >= O) o = O - 1;
                const int pw = row * 40 + ((part ^ ((row >> 3) & 3)) << 3);
                const size_t wb = ((size_t)t * O + o) * C + c0 + (part << 3);
                *(short8*)&Bh[pw] = *(const short8*)(wth + wb);
                *(short8*)&Bl[pw] = *(const short8*)(wtl + wb);
            }
            __syncthreads();
            const short8 a = *(const short8*)&As[ard];
            short8 al;
            if (ASPLIT) al = *(const short8*)&Alo[ard];
#pragma unroll
            for (int nt = 0; nt < NTN; ++nt) {
                const int brow = nt * 16 + ln15;
                const int brd = brow * 40 + (((lane >> 4) ^ ((brow >> 3) & 3)) << 3);
                const short8 bh = *(const short8*)&Bh[brd];
                acc[nt] = __builtin_amdgcn_mfma_f32_16x16x32_bf16(a, bh, acc[nt], 0, 0, 0);
                const short8 bl = *(const short8*)&Bl[brd];
                acc[nt] = __builtin_amdgcn_mfma_f32_16x16x32_bf16(a, bl, acc[nt], 0, 0, 0);
                if (ASPLIT)
                    acc[nt] = __builtin_amdgcn_mfma_f32_16x16x32_bf16(al, bh, acc[nt], 0, 0, 0);
            }
        }
    }

#pragma unroll
    for (int nt = 0; nt < NTN; ++nt) {
        const int o = obase + nt * 16 + ln15;
        if (o < O) {
            const float bv = bias[o];
#pragma unroll
            for (int r = 0; r < 4; ++r) {
                const int pp = p0 + wv * 16 + ((lane >> 4) << 2) + r;
                const float v = acc[nt][r] + bv;
                const size_t oidx = ((size_t)(b * O + o)) * HW + pp;
                if (EPI == 0)      ((float*)outv)[oidx] = v;
                else if (EPI == 1) ((float*)outv)[oidx] = tanhf(v);
                else               ((bf16*)outv)[oidx] = __float2bfloat16(v);
            }
        }
    }
}

// ---------------- instance norm ----------------
template<typename T>
__global__ __launch_bounds__(256) void inorm_kernel(T* __restrict__ buf,
                                                    float* __restrict__ resid,
                                                    int HW, int mode)
{
    __shared__ double sh0[256], sh1[256];
    const int pl = blockIdx.x;
    T* p = buf + (size_t)pl * HW;
    double s = 0.0, ss = 0.0;
    for (int i = threadIdx.x; i < HW; i += 256) {
        float v = LD(p + i);
        s += (double)v; ss += (double)v * (double)v;
    }
    sh0[threadIdx.x] = s; sh1[threadIdx.x] = ss;
    __syncthreads();
    for (int st = 128; st > 0; st >>= 1) {
        if (threadIdx.x < st) {
            sh0[threadIdx.x] += sh0[threadIdx.x + st];
            sh1[threadIdx.x] += sh1[threadIdx.x + st];
        }
        __syncthreads();
    }
    const double mean = sh0[0] / HW;
    const float m = (float)mean;
    const float var = (float)(sh1[0] / HW - mean * mean);
    const float inv = rsqrtf(var + 1e-5f);
    if (mode == 0) {
        for (int i = threadIdx.x; i < HW; i += 256) {
            float v = (LD(p + i) - m) * inv;
            ST(p + i, v > 0.f ? v : 0.f);
        }
    } else {
        float* r = resid + (size_t)pl * HW;
        for (int i = threadIdx.x; i < HW; i += 256)
            r[i] = r[i] + (LD(p + i) - m) * inv;
    }
}

// ---------------- offset_sum ----------------
__global__ void zero1_kernel(float* __restrict__ out) { if (threadIdx.x == 0) out[0] = 0.f; }

__global__ __launch_bounds__(256) void offsum_one(const float* __restrict__ om, int HW,
                                                  float* __restrict__ out)
{
    __shared__ double sh[256];
    const int n = 8 * 18 * HW;
    double s = 0.0;
    for (int i = blockIdx.x * 256 + threadIdx.x; i < n; i += gridDim.x * 256) {
        const int b = i / (18 * HW); const int r = i - b * 18 * HW;
        const int c = r / HW; const int p = r - c * HW;
        s += fabs((double)om[(size_t)(b * 27 + c) * HW + p]);
    }
    sh[threadIdx.x] = s;
    __syncthreads();
    for (int st = 128; st > 0; st >>= 1) {
        if (threadIdx.x < st) sh[threadIdx.x] += sh[threadIdx.x + st];
        __syncthreads();
    }
    if (threadIdx.x == 0) atomicAdd(out, (float)(0.5 * sh[0] / n));
}

// ---------------- launch ----------------
extern "C" void kernel_launch(void* const* d_in, const int* in_sizes, int n_in,
                              void* d_out, int out_size, void* d_ws, size_t ws_size,
                              hipStream_t stream)
{
    if (n_in < 27) return;
    if (out_size < 393217) return;
    if (in_sizes[0] != 8 * 256 * 32 * 32) return;
    if (in_sizes[1] != 8 * 128 * 64 * 64) return;
    if (in_sizes[2] != 8 * 256 * 32 * 32) return;
    if (in_sizes[25] != 128 * 128 * 9) return;
    if (in_sizes[26] != 128) return;

    const float* x        = (const float*)d_in[0];
    const float* skip1    = (const float*)d_in[1];
    const float* skip2    = (const float*)d_in[2];
    const float* rbw[2][2] = {{(const float*)d_in[3], (const float*)d_in[5]},
                              {(const float*)d_in[7], (const float*)d_in[9]}};
    const float* rbb[2][2] = {{(const float*)d_in[4], (const float*)d_in[6]},
                              {(const float*)d_in[8], (const float*)d_in[10]}};
    const float* conv1_w = (const float*)d_in[11]; const float* conv1_b = (const float*)d_in[12];
    const float* conv3_w = (const float*)d_in[13]; const float* conv3_b = (const float*)d_in[14];
    const float* conv5_w = (const float*)d_in[15]; const float* conv5_b = (const float*)d_in[16];
    const float* conv6_w = (const float*)d_in[17]; const float* conv6_b = (const float*)d_in[18];
    const float* dcn2_off_w = (const float*)d_in[19]; const float* dcn2_off_b = (const float*)d_in[20];
    const float* dcn2_w = (const float*)d_in[21]; const float* dcn2_b = (const float*)d_in[22];
    const float* dcn1_off_w = (const float*)d_in[23]; const float* dcn1_off_b = (const float*)d_in[24];
    const float* dcn1_w = (const float*)d_in[25]; const float* dcn1_b = (const float*)d_in[26];

    float* outp = (float*)d_out;

    const size_t NEED_F32 = 9494528ull;      // unchanged, proven R8-R17
    if (ws_size < NEED_F32 * 4ull) return;

    float* ws = (float*)d_ws;
    const size_t NA = 2097152ull;            // 8*256*32*32
    float* A   = ws;                          // x / rb accum / pre2 ; later Ib
    float* Bb  = ws + NA;                     // h / D ; later s1f(head) ; later Jb(lo half)
    float* Tmp = ws + 2 * NA;                 // rb tmp ; {wm2,wo2} ; conv3 lumped w ; s1f(tail) ; Jb(hi half)
    float* om2 = ws + 3 * NA;                 // [221184] ; after early offsum: wm1+wo1 / conv6 wt (padded)
    float* om1 = om2 + 221184;                // [884736] ; conv3 w spill ; later conv5 lumped w
    bf16*  Fb  = (bf16*)(om1 + 884736);       // c3 bf16 ; before conv3: early conv w / skip2 f32 NHWC
    bf16*  Ib  = (bf16*)A;                    // pre1 bf16
    bf16*  Jb  = (bf16*)Bb;                   // c5 bf16 (Bb+Tmp)
    u16*   wm2h = (u16*)Tmp;                  // mdcn2 MFMA w
    u16*   wm2l = wm2h + 589824;
    u16*   wo2h = (u16*)(Tmp + 589824);       // dcn2 off-conv MFMA w
    u16*   wo2l = wo2h + 124416;
    u16*   wL3h = (u16*)Tmp;                  // conv3 lumped w (spans Tmp+om2+om1 head)
    u16*   wL3l = wL3h + 30 * 65536;
    u16*   wC3h = wL3l + 30 * 65536;
    // dcn1 weights in om2 region (dead after early offsum; conv3 wL3 span dead by then)
    u16*   wm1h = (u16*)om2;                  // 2*147456 u16
    u16*   wm1l = wm1h + 147456;
    u16*   wo1h = wm1h + 294912;              // 2*62208 u16 (total 419328 <= 442368)
    u16*   wo1l = wo1h + 62208;
    u16*   wL5h = (u16*)om1;                  // conv5 lumped w (after offsum(om1))
    u16*   wL5l = wL5h + 30 * 16384;
    u16*   wC5h = wL5l + 30 * 16384;
    // conv6 padded weights [49][2][4][32][8] = 100352 u16 per half (om2 dead after mdcn1)
    u16*   wt6h = (u16*)om2;
    u16*   wt6l = wt6h + 100352;
    u16*   wEh = (u16*)Fb;                    // early conv MFMA weights (Fb free until conv3)
    // skip2 f32 NHWC: 2M f32 = 8MB = exactly the Fb region (free conv1->conv3)
    float* s2f = (float*)Fb;
    // skip1 f32 NHWC: 4M f32 = 16MB = Bb+Tmp contiguous (both dead after conv3)
    float* s1f = Bb;

    copy_kernel<<<8192, 256, 0, stream>>>(x, A, (int)NA);

    // ResBlocks via conv_mfma3 (A+W hi/lo split -> ~f32 precision)
    for (int r = 0; r < 2; ++r) {
        wsplit2_kernel<<<2304, 256, 0, stream>>>(rbw[r][0], wEh, wEh + 589824, 256, 256, 9);
        conv_mfma3<float, float, 3, false, 0, true, 4, 32, 2, 2, false><<<dim3(16, 8, 4), 256, 0, stream>>>(
            A, (const float*)nullptr, 256, 256, wEh, wEh + 589824, rbb[r][0], Bb, 256, 32, 32);
        inorm_kernel<float><<<2048, 256, 0, stream>>>(Bb, nullptr, 1024, 0);
        wsplit2_kernel<<<2304, 256, 0, stream>>>(rbw[r][1], wEh, wEh + 589824, 256, 256, 9);
        conv_mfma3<float, float, 3, false, 0, true, 4, 32, 2, 2, false><<<dim3(16, 8, 4), 256, 0, stream>>>(
            Bb, (const float*)nullptr, 256, 256, wEh, wEh + 589824, rbb[r][1], Tmp, 256, 32, 32);
        inorm_kernel<float><<<2048, 256, 0, stream>>>(Tmp, A, 1024, 1);
    }

    // conv1 (5x5, 256->256) via conv_mfma3 + IN/ReLU
    wsplit2_kernel<<<6400, 256, 0, stream>>>(conv1_w, wEh, wEh + 1638400, 256, 256, 25);
    conv_mfma3<float, float, 5, false, 0, true, 6, 32, 2, 2, false><<<dim3(16, 8, 4), 256, 0, stream>>>(
        A, (const float*)nullptr, 256, 256, wEh, wEh + 1638400, conv1_b, Bb, 256, 32, 32);
    inorm_kernel<float><<<2048, 256, 0, stream>>>(Bb, nullptr, 1024, 0);

    // skip2 -> f32 NHWC (Fb region free after conv1)
    nhwc_f32_kernel<<<dim3(16, 8, 8), 256, 0, stream>>>(skip2, s2f, 256, 1024);

    // dcn2: off-conv MFMA -> om2 ; mdcn_mfma (barrier-free, f32 NHWC) -> A (pre2 f32)
    wsplit_kernel<<<486, 256, 0, stream>>>(dcn2_off_w, wo2h, wo2l, 27, 512, 9);
    conv_mfma<float, float, 3, false, false, 2, 0, false><<<dim3(16, 8, 1), 256, 0, stream>>>(
        Bb, skip2, 256, 512, wo2h, wo2l, dcn2_off_b, om2, 27, 32, 32);
    wsplit2_kernel<<<2304, 256, 0, stream>>>(dcn2_w, wm2h, wm2l, 256, 256, 9);
    mdcn_mfma<float, true><<<dim3(16, 8, 4), 256, 0, stream>>>(
        s2f, om2, wm2h, wm2l, dcn2_b, A, 256, 256, 32, 32);

    // offset_sum(om2) hoisted: frees om2 region
    zero1_kernel<<<1, 64, 0, stream>>>(outp + 393216);
    offsum_one<<<64, 256, 0, stream>>>(om2, 1024, outp + 393216);

    // conv3: row-lumped subpixel conv (15 taps + exact border corr), 512->128 @64x64
    wsplitL_kernel<<<12800, 256, 0, stream>>>(conv3_w, wL3h, wL3l, wC3h, 128, 512);
    conv_mfma5<float, float, 4, 32, 4, 4><<<dim3(16, 8, 2), 512, 0, stream>>>(
        A, Bb, 256, 512, wL3h, wL3l, wC3h, conv3_b, Fb, 128, 64, 64);
    inorm_kernel<bf16><<<1024, 256, 0, stream>>>(Fb, nullptr, 4096, 0);

    // dcn1: off-conv MFMA -> om1 ; skip1 -> f32 NHWC ; mdcn_mfma -> Ib (pre1 bf16)
    wsplit_kernel<<<243, 256, 0, stream>>>(dcn1_off_w, wo1h, wo1l, 27, 256, 9);
    conv_mfma<bf16, float, 3, false, false, 2, 0, false><<<dim3(64, 8, 1), 256, 0, stream>>>(
        Fb, skip1, 128, 256, wo1h, wo1l, dcn1_off_b, om1, 27, 64, 64);
    wsplit2_kernel<<<576, 256, 0, stream>>>(dcn1_w, wm1h, wm1l, 128, 128, 9);
    nhwc_f32_kernel<<<dim3(64, 4, 8), 256, 0, stream>>>(skip1, s1f, 128, 4096);
    mdcn_mfma<bf16, true><<<dim3(64, 8, 2), 256, 0, stream>>>(
        s1f, om1, wm1h, wm1l, dcn1_b, Ib, 128, 128, 64, 64);

    // offset_sum(om1) (frees om1 for conv5 lumped weights)
    offsum_one<<<64, 256, 0, stream>>>(om1, 4096, outp + 393216);

    // conv5: row-lumped subpixel conv, 256->64 @128x128 -> Jb + IN/ReLU
    wsplitL_kernel<<<3200, 256, 0, stream>>>(conv5_w, wL5h, wL5l, wC5h, 64, 256);
    conv_mfma5<bf16, bf16, 3, 64, 4, 4><<<dim3(64, 8, 1), 512, 0, stream>>>(
        Ib, Fb, 128, 256, wL5h, wL5l, wC5h, conv5_b, Jb, 64, 128, 128);
    inorm_kernel<bf16><<<512, 256, 0, stream>>>(Jb, nullptr, 16384, 0);

    // conv6: 7x7, 64->3, tanh via conv_mfma3 (tiled staging, XCD-pinned, padded O=32)
    wsplit2p_kernel<<<392, 256, 0, stream>>>(conv6_w, wt6h, wt6l, 3, 32, 64, 49);
    conv_mfma3<bf16, float, 7, false, 3, false, 10, 128, 4, 8, true><<<dim3(32, 8, 1), 1024, 0, stream>>>(
        Jb, (const float*)nullptr, 64, 64, wt6h, wt6l, conv6_b, (void*)outp, 32, 128, 128);
}

// Round 10
// 1303.033 us; speedup vs baseline: 1.2130x; 1.2130x over previous
//
#include <hip/hip_runtime.h>
#include <hip/hip_bf16.h>
#include <math.h>

typedef __hip_bfloat16 bf16;
typedef unsigned short u16;
typedef __attribute__((ext_vector_type(8))) short short8;   // 8 bf16 (4 VGPRs)
typedef __attribute__((ext_vector_type(4))) float f32x4;

__device__ __forceinline__ float LD(const float* p) { return *p; }
__device__ __forceinline__ float LD(const bf16* p)  { return __bfloat162float(*p); }
__device__ __forceinline__ void  ST(float* p, float v) { *p = v; }
__device__ __forceinline__ void  ST(bf16* p, float v)  { *p = __float2bfloat16(v); }
__device__ __forceinline__ u16   f2b(float v) { bf16 h = __float2bfloat16(v); return *reinterpret_cast<u16*>(&h); }
__device__ __forceinline__ float b2fu(u16 u) { bf16 h = *reinterpret_cast<bf16*>(&u); return __bfloat162float(h); }

// ---------------- f32 copy ----------------
__global__ __launch_bounds__(256) void copy_kernel(const float* __restrict__ in,
                                                   float* __restrict__ out, int n) {
    int i = blockIdx.x * blockDim.x + threadIdx.x;
    if (i < n) out[i] = in[i];
}

// ---- NCHW f32 -> NHWC f32 (LDS-tiled transpose) ----
__global__ __launch_bounds__(256) void nhwc_f32_kernel(const float* __restrict__ in,
                                                       float* __restrict__ out,
                                                       int C, int HW)
{
    __shared__ float tile[32][65];
    const int b = blockIdx.z;
    const int c0 = blockIdx.y * 32;
    const int p0 = blockIdx.x * 64;
    for (int i = threadIdx.x; i < 2048; i += 256) {
        const int c_ = i >> 6, p_ = i & 63;
        tile[c_][p_] = in[((size_t)(b * C + c0 + c_)) * HW + p0 + p_];
    }
    __syncthreads();
    for (int i = threadIdx.x; i < 2048; i += 256) {
        const int p_ = i >> 5, c_ = i & 31;
        out[((size_t)b * HW + p0 + p_) * C + c0 + c_] = tile[c_][p_];
    }
}

// ---- wsplit (layout [t][o][c], for off-convs) ----
__global__ __launch_bounds__(256) void wsplit_kernel(const float* __restrict__ w,
                                                     u16* __restrict__ hi, u16* __restrict__ lo,
                                                     int O, int C, int KK)
{
    const int i = blockIdx.x * 256 + threadIdx.x;
    const int n = O * C * KK;
    if (i >= n) return;
    const int o = i / (C * KK);
    const int r = i - o * C * KK;
    const int c = r / KK;
    const int t = r - c * KK;
    const float v = w[i];
    const bf16 h = __float2bfloat16(v);
    const float hv = __bfloat162float(h);
    const bf16 l = __float2bfloat16(v - hv);
    const size_t dst = ((size_t)t * O + o) * C + c;
    hi[dst] = *(const u16*)&h;
    lo[dst] = *(const u16*)&l;
}

// ---- wsplit2: layout [t][cc][quad][O][8] for conv_mfma3 + mdcn_mfma ----
__global__ __launch_bounds__(256) void wsplit2_kernel(const float* __restrict__ w,
                                                      u16* __restrict__ hi, u16* __restrict__ lo,
                                                      int O, int C, int KK)
{
    const int i = blockIdx.x * 256 + threadIdx.x;
    const int n = O * C * KK;
    if (i >= n) return;
    const int o = i / (C * KK);
    const int r = i - o * C * KK;
    const int c = r / KK;
    const int t = r - c * KK;
    const float v = w[i];
    const bf16 h = __float2bfloat16(v);
    const float hv = __bfloat162float(h);
    const bf16 l = __float2bfloat16(v - hv);
    const int nch = C >> 5;
    const int cc = c >> 5, quad = (c >> 3) & 3, q = c & 7;
    const size_t dst = ((((size_t)t * nch + cc) * 4 + quad) * O + o) * 8 + q;
    hi[dst] = *(const u16*)&h;
    lo[dst] = *(const u16*)&l;
}

// ---- wsplit2p: like wsplit2 but zero-padded output channels to OP (conv6: O=3 -> OP=32) ----
__global__ __launch_bounds__(256) void wsplit2p_kernel(const float* __restrict__ w,
                                                       u16* __restrict__ hi, u16* __restrict__ lo,
                                                       int O, int OP, int C, int KK)
{
    const int i = blockIdx.x * 256 + threadIdx.x;
    const int n = OP * C * KK;
    if (i >= n) return;
    const int o = i / (C * KK);
    const int r = i - o * C * KK;
    const int c = r / KK;
    const int t = r - c * KK;
    float v = 0.f;
    if (o < O) v = w[((size_t)o * C + c) * KK + t];
    const bf16 h = __float2bfloat16(v);
    const float hv = __bfloat162float(h);
    const bf16 l = __float2bfloat16(v - hv);
    const int nch = C >> 5;
    const int cc = c >> 5, quad = (c >> 3) & 3, q = c & 7;
    const size_t dst = ((((size_t)t * nch + cc) * 4 + quad) * OP + o) * 8 + q;
    hi[dst] = *(const u16*)&h;
    lo[dst] = *(const u16*)&l;
}

// ---- wsplitL: row-lumped subpixel weights for conv_mfma5 (UP 5x5 -> 15 taps) ----
__global__ __launch_bounds__(256) void wsplitL_kernel(const float* __restrict__ w,
        u16* __restrict__ lh, u16* __restrict__ ll, u16* __restrict__ ch, int O, int C)
{
    const int i = blockIdx.x * 256 + threadIdx.x;
    const int n = O * C * 50;
    if (i >= n) return;
    const int s = i / (O * C);
    const int r = i - s * (O * C);
    const int o = r / C;
    const int c = r - o * C;
    const size_t U = (size_t)C * O;
    const int cc = c >> 5, quad = (c >> 3) & 3, q = c & 7;
    const size_t din = (((size_t)cc * 4 + quad) * O + o) * 8 + q;
    const float* wp = w + ((size_t)o * C + c) * 25;
    if (s < 30) {
        const int ry = s / 15, rem = s % 15, j = rem / 5, tx = rem % 5;
        int ys, yn;
        if (ry == 0) { ys = (j == 0) ? 0 : (j == 1) ? 2 : 4; yn = (j == 2) ? 1 : 2; }
        else         { ys = (j == 0) ? 0 : (j == 1) ? 1 : 3; yn = (j == 0) ? 1 : 2; }
        float v = 0.f;
        for (int ty = ys; ty < ys + yn; ++ty) v += wp[ty * 5 + tx];
        const bf16 h = __float2bfloat16(v);
        const bf16 l = __float2bfloat16(v - __bfloat162float(h));
        lh[(size_t)s * U + din] = *(const u16*)&h;
        ll[(size_t)s * U + din] = *(const u16*)&l;
    } else {
        const int t = s - 30;
        const int cidx = t / 5, tx = t - cidx * 5;
        const int tyc = (cidx == 0) ? 0 : (cidx == 1) ? 1 : (cidx == 2) ? 3 : 4;
        const bf16 h = __float2bfloat16(wp[tyc * 5 + tx]);
        ch[(size_t)t * U + din] = *(const u16*)&h;
    }
}

// ======== conv_mfma3: tiled-input MFMA conv, B direct from global (REFLECT pad) ========
template<typename T1, typename T2, int K, bool UP, int EPI, bool ASPLIT,
         int NR, int NCOL, int MT, int MW, bool XPIN>
__global__ __launch_bounds__(MW * 128) void conv_mfma3(
        const T1* __restrict__ src1, const T2* __restrict__ src2,
        int C1, int C,
        const u16* __restrict__ wth, const u16* __restrict__ wtl,
        const float* __restrict__ bias,
        void* __restrict__ outv, int O, int H, int W)
{
    constexpr int KK = K * K;
    constexpr int ATILE = NR * NCOL * 32;
    __shared__ __align__(16) u16 Ah[ATILE];
    __shared__ __align__(16) u16 Al[ASPLIT ? ATILE : 8];

    const int tid  = threadIdx.x;
    const int lane = tid & 63;
    const int wv   = tid >> 6;
    const int ln15 = lane & 15;
    const int quad = lane >> 4;
    const int mi = wv % MW, ni = wv / MW;
    int b, p0;
    if (XPIN) {
        const int flat = blockIdx.x + gridDim.x * blockIdx.y;
        b = flat & 7;
        p0 = (flat >> 3) * (MT * 16 * MW);
    } else {
        b = blockIdx.y;
        p0 = blockIdx.x * (MT * 16 * MW);
    }
    const int obase = blockIdx.z * 64;
    const int HW = H * W;
    const int SH = UP ? (H >> 1) : H;
    const int SW = UP ? (W >> 1) : W;
    const int SHW = SH * SW;
    const int PAD = K / 2;
    const int C2 = C - C1;
    const int nch = C >> 5;

    const int y0 = p0 / W;
    const int rbase = (y0 <= PAD) ? 0 : (UP ? ((y0 - PAD) >> 1) : (y0 - PAD));

    int rs[MT][K], cs[MT][K];
#pragma unroll
    for (int ms = 0; ms < MT; ++ms) {
        const int pm = p0 + mi * (MT * 16) + ms * 16 + ln15;
        const int ym = pm / W, xm = pm - ym * W;
#pragma unroll
        for (int tt = 0; tt < K; ++tt) {
            int yy = ym + tt - PAD;
            yy = yy < 0 ? -yy : yy; yy = yy >= H ? 2 * H - 2 - yy : yy;
            rs[ms][tt] = (UP ? (yy >> 1) : yy) - rbase;
            int xx = xm + tt - PAD;
            xx = xx < 0 ? -xx : xx; xx = xx >= W ? 2 * W - 2 - xx : xx;
            cs[ms][tt] = UP ? (xx >> 1) : xx;
        }
    }

    f32x4 acc[MT][2];
#pragma unroll
    for (int i = 0; i < MT; ++i)
#pragma unroll
        for (int j = 0; j < 2; ++j) acc[i][j] = (f32x4)0.f;

    for (int cc = 0; cc < nch; ++cc) {
        const int c0 = cc << 5;
        __syncthreads();
        for (int idx = tid; idx < NR * NCOL * 4; idx += MW * 128) {
            const int c_ = idx % NCOL;
            const int r_ = (idx / NCOL) % NR;
            const int cq = idx / (NCOL * NR);
            int rr = rbase + r_; rr = rr >= SH ? SH - 1 : rr;
            const int sidx = rr * SW + c_;
            short8 vh, vl;
#pragma unroll
            for (int q = 0; q < 8; ++q) {
                const int c = c0 + cq * 8 + q;
                float v;
                if (c < C1) v = LD(src1 + (size_t)(b * C1 + c) * SHW + sidx);
                else        v = LD(src2 + (size_t)(b * C2 + (c - C1)) * SHW + sidx);
                const u16 hv = f2b(v);
                vh[q] = (short)hv;
                if (ASPLIT) vl[q] = (short)f2b(v - b2fu(hv));
            }
            *(short8*)&Ah[idx * 8] = vh;
            if (ASPLIT) *(short8*)&Al[idx * 8] = vl;
        }
        __syncthreads();

#pragma unroll
        for (int t = 0; t < KK; ++t) {
            const int ty = t / K, tx = t - ty * K;
            const size_t wb0 = ((((size_t)t * nch + cc) * 4 + quad) * O
                                + obase + ni * 32 + ln15) * 8;
            const short8 b0h = *(const short8*)(wth + wb0);
            const short8 b1h = *(const short8*)(wth + wb0 + 128);
            const short8 b0l = *(const short8*)(wtl + wb0);
            const short8 b1l = *(const short8*)(wtl + wb0 + 128);
#pragma unroll
            for (int ms = 0; ms < MT; ++ms) {
                const int ao = ((quad * NR + rs[ms][ty]) * NCOL + cs[ms][tx]) * 8;
                const short8 a = *(const short8*)&Ah[ao];
                acc[ms][0] = __builtin_amdgcn_mfma_f32_16x16x32_bf16(a, b0h, acc[ms][0], 0, 0, 0);
                acc[ms][0] = __builtin_amdgcn_mfma_f32_16x16x32_bf16(a, b0l, acc[ms][0], 0, 0, 0);
                acc[ms][1] = __builtin_amdgcn_mfma_f32_16x16x32_bf16(a, b1h, acc[ms][1], 0, 0, 0);
                acc[ms][1] = __builtin_amdgcn_mfma_f32_16x16x32_bf16(a, b1l, acc[ms][1], 0, 0, 0);
                if (ASPLIT) {
                    const short8 al = *(const short8*)&Al[ao];
                    acc[ms][0] = __builtin_amdgcn_mfma_f32_16x16x32_bf16(al, b0h, acc[ms][0], 0, 0, 0);
                    acc[ms][1] = __builtin_amdgcn_mfma_f32_16x16x32_bf16(al, b1h, acc[ms][1], 0, 0, 0);
                }
            }
        }
    }

#pragma unroll
    for (int ms = 0; ms < MT; ++ms) {
#pragma unroll
        for (int ns = 0; ns < 2; ++ns) {
            const int o = obase + ni * 32 + ns * 16 + ln15;
            const float bv = (EPI == 3) ? (o < 3 ? bias[o] : 0.f) : bias[o];
            const f32x4 av = acc[ms][ns];
#pragma unroll
            for (int r = 0; r < 4; ++r) {
                const int pp = p0 + mi * (MT * 16) + ms * 16 + (quad << 2) + r;
                const float v = av[r] + bv;
                if (EPI == 0) {
                    ((float*)outv)[((size_t)(b * O + o)) * HW + pp] = v;
                } else if (EPI == 3) {
                    if (o < 3)
                        ((float*)outv)[((size_t)(b * 3 + o)) * HW + pp] = tanhf(v);
                } else {
                    ((bf16*)outv)[((size_t)(b * O + o)) * HW + pp] = __float2bfloat16(v);
                }
            }
        }
    }
}

// ======== conv_mfma5: row-lumped UP 5x5 conv (15 taps) with exact border corr ========
template<typename T1, typename T2, int NR, int NCOL, int MT, int MW>
__global__ __launch_bounds__(MW * 128) void conv_mfma5(
        const T1* __restrict__ src1, const T2* __restrict__ src2,
        int C1, int C,
        const u16* __restrict__ wLh, const u16* __restrict__ wLl,
        const u16* __restrict__ wCh,
        const float* __restrict__ bias,
        bf16* __restrict__ out, int O, int H, int W)
{
    constexpr int NRR = NR + 1;
    __shared__ __align__(16) u16 Ah[4 * NRR * NCOL * 8];

    const int tid  = threadIdx.x;
    const int lane = tid & 63;
    const int wv   = tid >> 6;
    const int ln15 = lane & 15;
    const int quad = lane >> 4;
    const int mi = wv % MW, ni = wv / MW;
    const int b = blockIdx.y;
    const int p0 = blockIdx.x * (MT * 16 * MW);
    const int obase = blockIdx.z * 64;
    const int HW = H * W;
    const int SH = H >> 1, SW = W >> 1;
    const int SHW = SH * SW;
    const int C2 = C - C1;
    const int nch = C >> 5;
    const size_t U = (size_t)C * O;

    const int y0 = p0 / W;
    const int rbase = (y0 <= 2) ? 0 : ((y0 - 2) >> 1);

    const int ym0 = (p0 + mi * (MT * 16)) / W;
    const int ry = ym0 & 1;
    const int uu = ym0 >> 1;
    int r0 = uu - 1, r2 = uu + 1;
    r0 = r0 < 0 ? 1 : r0;
    r2 = r2 >= SH ? SH - 2 : r2;
    const int rg0 = r0 - rbase, rg1 = uu - rbase, rg2 = r2 - rbase;

    const bool isTopW = (ym0 <= 1), isBotW = (ym0 >= H - 2);
    const bool isBorderW = isTopW || isBotW;
    int cidx = 0;
    if (isTopW) cidx = (ym0 == 0) ? 1 : 0;
    if (isBotW) cidx = (ym0 == H - 2) ? 3 : 2;
    const bool blkTop = (p0 == 0);
    const bool blkBot = (p0 + MW * MT * 16 == HW);
    const bool blkEdge = blkTop || blkBot;

    int cs[MT][5];
#pragma unroll
    for (int ms = 0; ms < MT; ++ms) {
        const int pm = p0 + mi * (MT * 16) + ms * 16 + ln15;
        const int xm = pm % W;
#pragma unroll
        for (int tt = 0; tt < 5; ++tt) {
            int xx = xm + tt - 2;
            xx = xx < 0 ? -xx : xx; xx = xx >= W ? 2 * W - 2 - xx : xx;
            cs[ms][tt] = xx >> 1;
        }
    }

    f32x4 acc[MT][2];
#pragma unroll
    for (int i = 0; i < MT; ++i)
#pragma unroll
        for (int j = 0; j < 2; ++j) acc[i][j] = (f32x4)0.f;

    for (int cc = 0; cc < nch; ++cc) {
        const int c0 = cc << 5;
        __syncthreads();
        for (int idx = tid; idx < NR * NCOL * 4; idx += MW * 128) {
            const int c_ = idx % NCOL;
            const int r_ = (idx / NCOL) % NR;
            const int cq = idx / (NCOL * NR);
            int rr = rbase + r_; rr = rr >= SH ? SH - 1 : rr;
            const int sidx = rr * SW + c_;
            short8 vh;
#pragma unroll
            for (int q = 0; q < 8; ++q) {
                const int c = c0 + cq * 8 + q;
                float v;
                if (c < C1) v = LD(src1 + (size_t)(b * C1 + c) * SHW + sidx);
                else        v = LD(src2 + (size_t)(b * C2 + (c - C1)) * SHW + sidx);
                vh[q] = (short)f2b(v);
            }
            *(short8*)&Ah[((cq * NRR + r_) * NCOL + c_) * 8] = vh;
        }
        if (blkEdge) {
            const int ra = blkTop ? 0 : SH - 1;
            const int rb2 = blkTop ? 1 : SH - 2;
            for (int idx = tid; idx < NCOL * 4; idx += MW * 128) {
                const int c_ = idx % NCOL;
                const int cq = idx / NCOL;
                short8 vh;
#pragma unroll
                for (int q = 0; q < 8; ++q) {
                    const int c = c0 + cq * 8 + q;
                    float va, vb;
                    if (c < C1) {
                        const size_t base = (size_t)(b * C1 + c) * SHW;
                        va = LD(src1 + base + ra * SW + c_);
                        vb = LD(src1 + base + rb2 * SW + c_);
                    } else {
                        const size_t base = (size_t)(b * C2 + (c - C1)) * SHW;
                        va = LD(src2 + base + ra * SW + c_);
                        vb = LD(src2 + base + rb2 * SW + c_);
                    }
                    vh[q] = (short)f2b(va - vb);
                }
                *(short8*)&Ah[((cq * NRR + NR) * NCOL + c_) * 8] = vh;
            }
        }
        __syncthreads();

        const size_t wq = ((size_t)(cc * 4 + quad) * O + obase + ni * 32 + ln15) * 8;
#pragma unroll
        for (int j = 0; j < 3; ++j) {
            const int rgj = (j == 0) ? rg0 : (j == 1) ? rg1 : rg2;
#pragma unroll
            for (int tx = 0; tx < 5; ++tx) {
                const size_t wb = (size_t)((ry * 3 + j) * 5 + tx) * U + wq;
                const short8 b0h = *(const short8*)(wLh + wb);
                const short8 b1h = *(const short8*)(wLh + wb + 128);
                const short8 b0l = *(const short8*)(wLl + wb);
                const short8 b1l = *(const short8*)(wLl + wb + 128);
#pragma unroll
                for (int ms = 0; ms < MT; ++ms) {
                    const int ao = ((quad * NRR + rgj) * NCOL + cs[ms][tx]) * 8;
                    const short8 a = *(const short8*)&Ah[ao];
                    acc[ms][0] = __builtin_amdgcn_mfma_f32_16x16x32_bf16(a, b0h, acc[ms][0], 0, 0, 0);
                    acc[ms][0] = __builtin_amdgcn_mfma_f32_16x16x32_bf16(a, b0l, acc[ms][0], 0, 0, 0);
                    acc[ms][1] = __builtin_amdgcn_mfma_f32_16x16x32_bf16(a, b1h, acc[ms][1], 0, 0, 0);
                    acc[ms][1] = __builtin_amdgcn_mfma_f32_16x16x32_bf16(a, b1l, acc[ms][1], 0, 0, 0);
                }
            }
        }
        if (isBorderW) {
#pragma unroll
            for (int tx = 0; tx < 5; ++tx) {
                const size_t wb = (size_t)(cidx * 5 + tx) * U + wq;
                const short8 b0 = *(const short8*)(wCh + wb);
                const short8 b1 = *(const short8*)(wCh + wb + 128);
#pragma unroll
                for (int ms = 0; ms < MT; ++ms) {
                    const int ao = ((quad * NRR + NR) * NCOL + cs[ms][tx]) * 8;
                    const short8 a = *(const short8*)&Ah[ao];
                    acc[ms][0] = __builtin_amdgcn_mfma_f32_16x16x32_bf16(a, b0, acc[ms][0], 0, 0, 0);
                    acc[ms][1] = __builtin_amdgcn_mfma_f32_16x16x32_bf16(a, b1, acc[ms][1], 0, 0, 0);
                }
            }
        }
    }

#pragma unroll
    for (int ms = 0; ms < MT; ++ms) {
#pragma unroll
        for (int ns = 0; ns < 2; ++ns) {
            const int o = obase + ni * 32 + ns * 16 + ln15;
            const float bv = bias[o];
            const f32x4 av = acc[ms][ns];
#pragma unroll
            for (int r = 0; r < 4; ++r) {
                const int pp = p0 + mi * (MT * 16) + ms * 16 + (quad << 2) + r;
                out[((size_t)(b * O + o)) * HW + pp] = __float2bfloat16(av[r] + bv);
            }
        }
    }
}

// ========== mdcn_mfma: deformable conv, LDS A-staging + o-fold (OF o-blocks/block) ==========
// XCD-pinned (b = flat&7). f32 NHWC gather, k-outer (R8 proven structure). Each block
// computes OF o-blocks from ONE A-staging: B fragments loaded direct from global
// (weights are batch-independent -> fully L2-resident on every XCD). Gather-transaction
// count per output divided by OF (mdcn is gather-transaction bound, R9 evidence).
template<typename OT, bool ASPLIT, int OF>
__global__ __launch_bounds__(256) void mdcn_mfma(
        const float* __restrict__ skipf,
        const float* __restrict__ om,
        const u16* __restrict__ wth, const u16* __restrict__ wtl,
        const float* __restrict__ bias,
        OT* __restrict__ out, int C, int O, int H, int W)
{
    __shared__ float tpy[576], tpxs[576], tms[576];
    __shared__ __align__(16) u16 Ah[2][2048];
    __shared__ __align__(16) u16 Al[ASPLIT ? 2 : 1][2048];

    const int tid = threadIdx.x;
    const int lane = tid & 63;
    const int wv = tid >> 6;
    const int ln15 = lane & 15;
    const int quad = lane >> 4;
    const int mi = wv & 1, ni = wv >> 1;
    const int flat = blockIdx.x + gridDim.x * (blockIdx.y + 8 * blockIdx.z);
    const int b = flat & 7;
    const int rest = flat >> 3;
    const int p0 = (rest % gridDim.x) * 64;
    const int obase0 = (rest / gridDim.x) * (OF * 64);
    const int HW = H * W;
    const int nch = C >> 5;

    const float* omb = om + (size_t)b * 27 * HW;
    for (int i = tid; i < 576; i += 256) {
        const int k = i >> 6, px_ = i & 63;
        const int p = p0 + px_;
        const int y = p / W, x = p - y * W;
        const float dy = omb[(2 * k) * HW + p];
        const float dx = omb[(2 * k + 1) * HW + p];
        const float mk = 1.f / (1.f + expf(-omb[(18 + k) * HW + p]));
        float py = (float)(y + k / 3 - 1) + dy;
        float pxx = (float)(x + k % 3 - 1) + dx;
        py  = fminf(fmaxf(py, -2.f), (float)H + 1.f);
        pxx = fminf(fmaxf(pxx, -2.f), (float)W + 1.f);
        tpy[i] = py; tpxs[i] = pxx; tms[i] = mk;
    }
    __syncthreads();

    f32x4 acc[OF][2][2];
#pragma unroll
    for (int z = 0; z < OF; ++z)
#pragma unroll
        for (int i = 0; i < 2; ++i)
#pragma unroll
            for (int j = 0; j < 2; ++j) acc[z][i][j] = (f32x4)0.f;

    const float* xb = skipf + (size_t)b * HW * C;
    const int swA = (lane >> 1) & 3;
    const int awr = (lane * 4 + (wv ^ swA)) * 8;
    const int pix0 = mi * 32 + ln15;
    const int pix1 = pix0 + 16;
    const int ao0 = (pix0 * 4 + (quad ^ ((pix0 >> 1) & 3))) * 8;
    const int ao1 = (pix1 * 4 + (quad ^ ((pix1 >> 1) & 3))) * 8;

    int chunk = 0;
    for (int k = 0; k < 9; ++k) {
        // bilinear params once per k (registers, reused across all cc)
        const float py = tpy[k * 64 + lane], pxx = tpxs[k * 64 + lane], mk = tms[k * 64 + lane];
        const float y0f = floorf(py), x0f = floorf(pxx);
        const int y0 = (int)y0f, x0 = (int)x0f;
        const float wy1 = py - y0f, wx1 = pxx - x0f;
        const float wy0 = 1.f - wy1, wx0 = 1.f - wx1;
        const bool r0v = (y0 >= 0 && y0 < H), r1v = (y0 + 1 >= 0 && y0 + 1 < H);
        const bool c0v = (x0 >= 0 && x0 < W), c1v = (x0 + 1 >= 0 && x0 + 1 < W);
        const float w00 = (r0v && c0v) ? wy0 * wx0 * mk : 0.f;
        const float w01 = (r0v && c1v) ? wy0 * wx1 * mk : 0.f;
        const float w10 = (r1v && c0v) ? wy1 * wx0 * mk : 0.f;
        const float w11 = (r1v && c1v) ? wy1 * wx1 * mk : 0.f;
        const int i00 = (r0v ? y0 : 0) * W + (c0v ? x0 : 0);
        const int i01 = (r0v ? y0 : 0) * W + (c1v ? x0 + 1 : 0);
        const int i10 = (r1v ? y0 + 1 : 0) * W + (c0v ? x0 : 0);
        const int i11 = (r1v ? y0 + 1 : 0) * W + (c1v ? x0 + 1 : 0);
        const float* pt00 = xb + (size_t)i00 * C;
        const float* pt01 = xb + (size_t)i01 * C;
        const float* pt10 = xb + (size_t)i10 * C;
        const float* pt11 = xb + (size_t)i11 * C;
        for (int cc = 0; cc < nch; ++cc, ++chunk) {
            const int s = chunk & 1;
            const int cbase = (cc << 5) + (wv << 3);
            {
                const f32x4 a00 = *(const f32x4*)(pt00 + cbase);
                const f32x4 b00 = *(const f32x4*)(pt00 + cbase + 4);
                const f32x4 a01 = *(const f32x4*)(pt01 + cbase);
                const f32x4 b01 = *(const f32x4*)(pt01 + cbase + 4);
                const f32x4 a10 = *(const f32x4*)(pt10 + cbase);
                const f32x4 b10 = *(const f32x4*)(pt10 + cbase + 4);
                const f32x4 a11 = *(const f32x4*)(pt11 + cbase);
                const f32x4 b11 = *(const f32x4*)(pt11 + cbase + 4);
                short8 vh, vl;
#pragma unroll
                for (int q = 0; q < 4; ++q) {
                    const float v = w00 * a00[q] + w01 * a01[q] + w10 * a10[q] + w11 * a11[q];
                    const u16 hv = f2b(v);
                    vh[q] = (short)hv;
                    if (ASPLIT) vl[q] = (short)f2b(v - b2fu(hv));
                }
#pragma unroll
                for (int q = 0; q < 4; ++q) {
                    const float v = w00 * b00[q] + w01 * b01[q] + w10 * b10[q] + w11 * b11[q];
                    const u16 hv = f2b(v);
                    vh[4 + q] = (short)hv;
                    if (ASPLIT) vl[4 + q] = (short)f2b(v - b2fu(hv));
                }
                *(short8*)&Ah[s][awr] = vh;
                if (ASPLIT) *(short8*)&Al[s][awr] = vl;
            }
            __syncthreads();
            const short8 a0 = *(const short8*)&Ah[s][ao0];
            const short8 a1 = *(const short8*)&Ah[s][ao1];
            short8 a0l, a1l;
            if (ASPLIT) {
                a0l = *(const short8*)&Al[s][ao0];
                a1l = *(const short8*)&Al[s][ao1];
            }
#pragma unroll
            for (int zo = 0; zo < OF; ++zo) {
                const size_t base = ((((size_t)k * nch + cc) * 4 + quad) * O
                                     + obase0 + zo * 64 + ni * 32 + ln15) * 8;
                const short8 b0h = *(const short8*)(wth + base);
                const short8 b1h = *(const short8*)(wth + base + 128);
                const short8 b0l = *(const short8*)(wtl + base);
                const short8 b1l = *(const short8*)(wtl + base + 128);
                acc[zo][0][0] = __builtin_amdgcn_mfma_f32_16x16x32_bf16(a0, b0h, acc[zo][0][0], 0, 0, 0);
                acc[zo][0][0] = __builtin_amdgcn_mfma_f32_16x16x32_bf16(a0, b0l, acc[zo][0][0], 0, 0, 0);
                acc[zo][0][1] = __builtin_amdgcn_mfma_f32_16x16x32_bf16(a0, b1h, acc[zo][0][1], 0, 0, 0);
                acc[zo][0][1] = __builtin_amdgcn_mfma_f32_16x16x32_bf16(a0, b1l, acc[zo][0][1], 0, 0, 0);
                acc[zo][1][0] = __builtin_amdgcn_mfma_f32_16x16x32_bf16(a1, b0h, acc[zo][1][0], 0, 0, 0);
                acc[zo][1][0] = __builtin_amdgcn_mfma_f32_16x16x32_bf16(a1, b0l, acc[zo][1][0], 0, 0, 0);
                acc[zo][1][1] = __builtin_amdgcn_mfma_f32_16x16x32_bf16(a1, b1h, acc[zo][1][1], 0, 0, 0);
                acc[zo][1][1] = __builtin_amdgcn_mfma_f32_16x16x32_bf16(a1, b1l, acc[zo][1][1], 0, 0, 0);
                if (ASPLIT) {
                    acc[zo][0][0] = __builtin_amdgcn_mfma_f32_16x16x32_bf16(a0l, b0h, acc[zo][0][0], 0, 0, 0);
                    acc[zo][0][1] = __builtin_amdgcn_mfma_f32_16x16x32_bf16(a0l, b1h, acc[zo][0][1], 0, 0, 0);
                    acc[zo][1][0] = __builtin_amdgcn_mfma_f32_16x16x32_bf16(a1l, b0h, acc[zo][1][0], 0, 0, 0);
                    acc[zo][1][1] = __builtin_amdgcn_mfma_f32_16x16x32_bf16(a1l, b1h, acc[zo][1][1], 0, 0, 0);
                }
            }
        }
    }

#pragma unroll
    for (int zo = 0; zo < OF; ++zo) {
#pragma unroll
        for (int ms = 0; ms < 2; ++ms) {
#pragma unroll
            for (int ns = 0; ns < 2; ++ns) {
                const int o = obase0 + zo * 64 + ni * 32 + ns * 16 + ln15;
                const float bv = bias[o];
#pragma unroll
                for (int r = 0; r < 4; ++r) {
                    const int pp = p0 + mi * 32 + ms * 16 + (quad << 2) + r;
                    ST(out + ((size_t)(b * O + o)) * HW + pp, acc[zo][ms][ns][r] + bv);
                }
            }
        }
    }
}

// ================= conv_mfma — off-convs, XCD-pinned by batch =================
template<typename T1, typename T2, int K, bool REFLECT, bool UP, int NTN, int EPI, bool ASPLIT>
__global__ __launch_bounds__(256) void conv_mfma(
        const T1* __restrict__ src1, const T2* __restrict__ src2,
        int C1, int C,
        const u16* __restrict__ wth, const u16* __restrict__ wtl,
        const float* __restrict__ bias,
        void* __restrict__ outv, int O, int H, int W)
{
    constexpr int KK = K * K;
    __shared__ __align__(16) u16 As[64 * 40];
    __shared__ __align__(16) u16 Alo[ASPLIT ? 64 * 40 : 8];
    __shared__ __align__(16) u16 Bh[NTN * 16 * 40];
    __shared__ __align__(16) u16 Bl[NTN * 16 * 40];

    const int tid  = threadIdx.x;
    const int wv   = tid >> 6;
    const int lane = tid & 63;
    const int ln15 = lane & 15;
    const int flat = blockIdx.x + gridDim.x * blockIdx.y;
    const int b    = flat & 7;
    const int p0   = (flat >> 3) * 64;
    const int obase = blockIdx.z * (NTN * 16);
    const int HW = H * W;
    const int Hs = UP ? (H >> 1) : H;
    const int Ws = UP ? (W >> 1) : W;
    const int HsWs = Hs * Ws;
    const int PAD = K / 2;
    const int C2 = C - C1;
    const int m_stage = tid & 63;

    const int p = p0 + m_stage;
    const int y = p / W, x = p - y * W;
    int off[KK];
    float msk[KK];
#pragma unroll
    for (int ty = 0; ty < K; ++ty) {
#pragma unroll
        for (int tx = 0; tx < K; ++tx) {
            int yy = y + ty - PAD, xx = x + tx - PAD;
            bool vv = true;
            if (REFLECT) {
                yy = yy < 0 ? -yy : yy; yy = yy >= H ? 2 * H - 2 - yy : yy;
                xx = xx < 0 ? -xx : xx; xx = xx >= W ? 2 * W - 2 - xx : xx;
            } else {
                vv = (yy >= 0 && yy < H && xx >= 0 && xx < W);
                yy = yy < 0 ? 0 : (yy >= H ? H - 1 : yy);
                xx = xx < 0 ? 0 : (xx >= W ? W - 1 : xx);
            }
            off[ty * K + tx] = (UP ? (yy >> 1) : yy) * Ws + (UP ? (xx >> 1) : xx);
            msk[ty * K + tx] = vv ? 1.f : 0.f;
        }
    }

    f32x4 acc[NTN];
#pragma unroll
    for (int nt = 0; nt < NTN; ++nt) acc[nt] = (f32x4)0.f;

    const int aswz = (m_stage >> 3) & 3;
    const int awr  = m_stage * 40 + ((wv ^ aswz) << 3);
    const int arow = wv * 16 + ln15;
    const int ard  = arow * 40 + (((lane >> 4) ^ ((arow >> 3) & 3)) << 3);

    const int nch = C >> 5;
    for (int cc = 0; cc < nch; ++cc) {
        const int c0 = cc << 5;
        for (int t = 0; t < KK; ++t) {
            const int offt = off[t];
            const float mskt = msk[t];
            __syncthreads();
            {
                short8 avh, avl;
#pragma unroll
                for (int q = 0; q < 8; ++q) {
                    const int c = c0 + (wv << 3) + q;
                    float v;
                    if (c < C1) v = LD(src1 + ((size_t)(b * C1 + c)) * HsWs + offt);
                    else        v = LD(src2 + ((size_t)(b * C2 + (c - C1))) * HsWs + offt);
                    if (!REFLECT) v *= mskt;
                    const u16 hv = f2b(v);
                    avh[q] = (short)hv;
                    if (ASPLIT) avl[q] = (short)f2b(v - b2fu(hv));
                }
                *(short8*)&As[awr] = avh;
                if (ASPLIT) *(short8*)&Alo[awr] = avl;
            }
            for (int i = tid; i < NTN * 16 * 4; i += 256) {
                const int row = i >> 2, part = i & 3;
                int o = obase + row; if (o >= O) o = O - 1;
                const int pw = row * 40 + ((part ^ ((row >> 3) & 3)) << 3);
                const size_t wb = ((size_t)t * O + o) * C + c0 + (part << 3);
                *(short8*)&Bh[pw] = *(const short8*)(wth + wb);
                *(short8*)&Bl[pw] = *(const short8*)(wtl + wb);
            }
            __syncthreads();
            const short8 a = *(const short8*)&As[ard];
            short8 al;
            if (ASPLIT) al = *(const short8*)&Alo[ard];
#pragma unroll
            for (int nt = 0; nt < NTN; ++nt) {
                const int brow = nt * 16 + ln15;
                const int brd = brow * 40 + (((lane >> 4) ^ ((brow >> 3) & 3)) << 3);
                const short8 bh = *(const short8*)&Bh[brd];
                acc[nt] = __builtin_amdgcn_mfma_f32_16x16x32_bf16(a, bh, acc[nt], 0, 0, 0);
                const short8 bl = *(const short8*)&Bl[brd];
                acc[nt] = __builtin_amdgcn_mfma_f32_16x16x32_bf16(a, bl, acc[nt], 0, 0, 0);
                if (ASPLIT)
                    acc[nt] = __builtin_amdgcn_mfma_f32_16x16x32_bf16(al, bh, acc[nt], 0, 0, 0);
            }
        }
    }

#pragma unroll
    for (int nt = 0; nt < NTN; ++nt) {
        const int o = obase + nt * 16 + ln15;
        if (o < O) {
            const float bv = bias[o];
#pragma unroll
            for (int r = 0; r < 4; ++r) {
                const int pp = p0 + wv * 16 + ((lane >> 4) << 2) + r;
                const float v = acc[nt][r] + bv;
                const size_t oidx = ((size_t)(b * O + o)) * HW + pp;
                if (EPI == 0)      ((float*)outv)[oidx] = v;
                else if (EPI == 1) ((float*)outv)[oidx] = tanhf(v);
                else               ((bf16*)outv)[oidx] = __float2bfloat16(v);
            }
        }
    }
}

// ---------------- instance norm ----------------
template<typename T>
__global__ __launch_bounds__(256) void inorm_kernel(T* __restrict__ buf,
                                                    float* __restrict__ resid,
                                                    int HW, int mode)
{
    __shared__ double sh0[256], sh1[256];
    const int pl = blockIdx.x;
    T* p = buf + (size_t)pl * HW;
    double s = 0.0, ss = 0.0;
    for (int i = threadIdx.x; i < HW; i += 256) {
        float v = LD(p + i);
        s += (double)v; ss += (double)v * (double)v;
    }
    sh0[threadIdx.x] = s; sh1[threadIdx.x] = ss;
    __syncthreads();
    for (int st = 128; st > 0; st >>= 1) {
        if (threadIdx.x < st) {
            sh0[threadIdx.x] += sh0[threadIdx.x + st];
            sh1[threadIdx.x] += sh1[threadIdx.x + st];
        }
        __syncthreads();
    }
    const double mean = sh0[0] / HW;
    const float m = (float)mean;
    const float var = (float)(sh1[0] / HW - mean * mean);
    const float inv = rsqrtf(var + 1e-5f);
    if (mode == 0) {
        for (int i = threadIdx.x; i < HW; i += 256) {
            float v = (LD(p + i) - m) * inv;
            ST(p + i, v > 0.f ? v : 0.f);
        }
    } else {
        float* r = resid + (size_t)pl * HW;
        for (int i = threadIdx.x; i < HW; i += 256)
            r[i] = r[i] + (LD(p + i) - m) * inv;
    }
}

// ---------------- offset_sum ----------------
__global__ void zero1_kernel(float* __restrict__ out) { if (threadIdx.x == 0) out[0] = 0.f; }

__global__ __launch_bounds__(256) void offsum_one(const float* __restrict__ om, int HW,
                                                  float* __restrict__ out)
{
    __shared__ double sh[256];
    const int n = 8 * 18 * HW;
    double s = 0.0;
    for (int i = blockIdx.x * 256 + threadIdx.x; i < n; i += gridDim.x * 256) {
        const int b = i / (18 * HW); const int r = i - b * 18 * HW;
        const int c = r / HW; const int p = r - c * HW;
        s += fabs((double)om[(size_t)(b * 27 + c) * HW + p]);
    }
    sh[threadIdx.x] = s;
    __syncthreads();
    for (int st = 128; st > 0; st >>= 1) {
        if (threadIdx.x < st) sh[threadIdx.x] += sh[threadIdx.x + st];
        __syncthreads();
    }
    if (threadIdx.x == 0) atomicAdd(out, (float)(0.5 * sh[0] / n));
}

// ---------------- launch ----------------
extern "C" void kernel_launch(void* const* d_in, const int* in_sizes, int n_in,
                              void* d_out, int out_size, void* d_ws, size_t ws_size,
                              hipStream_t stream)
{
    if (n_in < 27) return;
    if (out_size < 393217) return;
    if (in_sizes[0] != 8 * 256 * 32 * 32) return;
    if (in_sizes[1] != 8 * 128 * 64 * 64) return;
    if (in_sizes[2] != 8 * 256 * 32 * 32) return;
    if (in_sizes[25] != 128 * 128 * 9) return;
    if (in_sizes[26] != 128) return;

    const float* x        = (const float*)d_in[0];
    const float* skip1    = (const float*)d_in[1];
    const float* skip2    = (const float*)d_in[2];
    const float* rbw[2][2] = {{(const float*)d_in[3], (const float*)d_in[5]},
                              {(const float*)d_in[7], (const float*)d_in[9]}};
    const float* rbb[2][2] = {{(const float*)d_in[4], (const float*)d_in[6]},
                              {(const float*)d_in[8], (const float*)d_in[10]}};
    const float* conv1_w = (const float*)d_in[11]; const float* conv1_b = (const float*)d_in[12];
    const float* conv3_w = (const float*)d_in[13]; const float* conv3_b = (const float*)d_in[14];
    const float* conv5_w = (const float*)d_in[15]; const float* conv5_b = (const float*)d_in[16];
    const float* conv6_w = (const float*)d_in[17]; const float* conv6_b = (const float*)d_in[18];
    const float* dcn2_off_w = (const float*)d_in[19]; const float* dcn2_off_b = (const float*)d_in[20];
    const float* dcn2_w = (const float*)d_in[21]; const float* dcn2_b = (const float*)d_in[22];
    const float* dcn1_off_w = (const float*)d_in[23]; const float* dcn1_off_b = (const float*)d_in[24];
    const float* dcn1_w = (const float*)d_in[25]; const float* dcn1_b = (const float*)d_in[26];

    float* outp = (float*)d_out;

    const size_t NEED_F32 = 9494528ull;      // unchanged, proven R8-R17
    if (ws_size < NEED_F32 * 4ull) return;

    float* ws = (float*)d_ws;
    const size_t NA = 2097152ull;            // 8*256*32*32
    float* A   = ws;                          // x / rb accum / pre2 ; later Ib
    float* Bb  = ws + NA;                     // h / D ; later s1f(head) ; later Jb(lo half)
    float* Tmp = ws + 2 * NA;                 // rb tmp ; {wm2,wo2} ; conv3 lumped w ; s1f(tail) ; Jb(hi half)
    float* om2 = ws + 3 * NA;                 // [221184] ; after early offsum: wm1+wo1 / conv6 wt (padded)
    float* om1 = om2 + 221184;                // [884736] ; conv3 w spill ; later conv5 lumped w
    bf16*  Fb  = (bf16*)(om1 + 884736);       // c3 bf16 ; before conv3: early conv w / skip2 f32 NHWC
    bf16*  Ib  = (bf16*)A;                    // pre1 bf16
    bf16*  Jb  = (bf16*)Bb;                   // c5 bf16 (Bb+Tmp)
    u16*   wm2h = (u16*)Tmp;                  // mdcn2 MFMA w
    u16*   wm2l = wm2h + 589824;
    u16*   wo2h = (u16*)(Tmp + 589824);       // dcn2 off-conv MFMA w
    u16*   wo2l = wo2h + 124416;
    u16*   wL3h = (u16*)Tmp;                  // conv3 lumped w (spans Tmp+om2+om1 head)
    u16*   wL3l = wL3h + 30 * 65536;
    u16*   wC3h = wL3l + 30 * 65536;
    // dcn1 weights in om2 region (dead after early offsum; conv3 wL3 span dead by then)
    u16*   wm1h = (u16*)om2;                  // 2*147456 u16
    u16*   wm1l = wm1h + 147456;
    u16*   wo1h = wm1h + 294912;              // 2*62208 u16 (total 419328 <= 442368)
    u16*   wo1l = wo1h + 62208;
    u16*   wL5h = (u16*)om1;                  // conv5 lumped w (after offsum(om1))
    u16*   wL5l = wL5h + 30 * 16384;
    u16*   wC5h = wL5l + 30 * 16384;
    // conv6 padded weights [49][2][4][32][8] = 100352 u16 per half (om2 dead after mdcn1)
    u16*   wt6h = (u16*)om2;
    u16*   wt6l = wt6h + 100352;
    u16*   wEh = (u16*)Fb;                    // early conv MFMA weights (Fb free until conv3)
    // skip2 f32 NHWC: 2M f32 = 8MB = exactly the Fb region (free conv1->conv3)
    float* s2f = (float*)Fb;
    // skip1 f32 NHWC: 4M f32 = 16MB = Bb+Tmp contiguous (both dead after conv3)
    float* s1f = Bb;

    copy_kernel<<<8192, 256, 0, stream>>>(x, A, (int)NA);

    // ResBlocks via conv_mfma3 (A+W hi/lo split -> ~f32 precision)
    for (int r = 0; r < 2; ++r) {
        wsplit2_kernel<<<2304, 256, 0, stream>>>(rbw[r][0], wEh, wEh + 589824, 256, 256, 9);
        conv_mfma3<float, float, 3, false, 0, true, 4, 32, 2, 2, false><<<dim3(16, 8, 4), 256, 0, stream>>>(
            A, (const float*)nullptr, 256, 256, wEh, wEh + 589824, rbb[r][0], Bb, 256, 32, 32);
        inorm_kernel<float><<<2048, 256, 0, stream>>>(Bb, nullptr, 1024, 0);
        wsplit2_kernel<<<2304, 256, 0, stream>>>(rbw[r][1], wEh, wEh + 589824, 256, 256, 9);
        conv_mfma3<float, float, 3, false, 0, true, 4, 32, 2, 2, false><<<dim3(16, 8, 4), 256, 0, stream>>>(
            Bb, (const float*)nullptr, 256, 256, wEh, wEh + 589824, rbb[r][1], Tmp, 256, 32, 32);
        inorm_kernel<float><<<2048, 256, 0, stream>>>(Tmp, A, 1024, 1);
    }

    // conv1 (5x5, 256->256) via conv_mfma3 + IN/ReLU
    wsplit2_kernel<<<6400, 256, 0, stream>>>(conv1_w, wEh, wEh + 1638400, 256, 256, 25);
    conv_mfma3<float, float, 5, false, 0, true, 6, 32, 2, 2, false><<<dim3(16, 8, 4), 256, 0, stream>>>(
        A, (const float*)nullptr, 256, 256, wEh, wEh + 1638400, conv1_b, Bb, 256, 32, 32);
    inorm_kernel<float><<<2048, 256, 0, stream>>>(Bb, nullptr, 1024, 0);

    // skip2 -> f32 NHWC (Fb region free after conv1)
    nhwc_f32_kernel<<<dim3(16, 8, 8), 256, 0, stream>>>(skip2, s2f, 256, 1024);

    // dcn2: off-conv MFMA -> om2 ; mdcn_mfma (OF=2: 2 o-blocks per A-staging) -> A
    wsplit_kernel<<<486, 256, 0, stream>>>(dcn2_off_w, wo2h, wo2l, 27, 512, 9);
    conv_mfma<float, float, 3, false, false, 2, 0, false><<<dim3(16, 8, 1), 256, 0, stream>>>(
        Bb, skip2, 256, 512, wo2h, wo2l, dcn2_off_b, om2, 27, 32, 32);
    wsplit2_kernel<<<2304, 256, 0, stream>>>(dcn2_w, wm2h, wm2l, 256, 256, 9);
    mdcn_mfma<float, true, 2><<<dim3(16, 8, 2), 256, 0, stream>>>(
        s2f, om2, wm2h, wm2l, dcn2_b, A, 256, 256, 32, 32);

    // offset_sum(om2) hoisted: frees om2 region
    zero1_kernel<<<1, 64, 0, stream>>>(outp + 393216);
    offsum_one<<<64, 256, 0, stream>>>(om2, 1024, outp + 393216);

    // conv3: row-lumped subpixel conv (15 taps + exact border corr), 512->128 @64x64
    wsplitL_kernel<<<12800, 256, 0, stream>>>(conv3_w, wL3h, wL3l, wC3h, 128, 512);
    conv_mfma5<float, float, 4, 32, 4, 4><<<dim3(16, 8, 2), 512, 0, stream>>>(
        A, Bb, 256, 512, wL3h, wL3l, wC3h, conv3_b, Fb, 128, 64, 64);
    inorm_kernel<bf16><<<1024, 256, 0, stream>>>(Fb, nullptr, 4096, 0);

    // dcn1: off-conv MFMA -> om1 ; skip1 -> f32 NHWC ; mdcn_mfma (OF=2) -> Ib (pre1 bf16)
    wsplit_kernel<<<243, 256, 0, stream>>>(dcn1_off_w, wo1h, wo1l, 27, 256, 9);
    conv_mfma<bf16, float, 3, false, false, 2, 0, false><<<dim3(64, 8, 1), 256, 0, stream>>>(
        Fb, skip1, 128, 256, wo1h, wo1l, dcn1_off_b, om1, 27, 64, 64);
    wsplit2_kernel<<<576, 256, 0, stream>>>(dcn1_w, wm1h, wm1l, 128, 128, 9);
    nhwc_f32_kernel<<<dim3(64, 4, 8), 256, 0, stream>>>(skip1, s1f, 128, 4096);
    mdcn_mfma<bf16, true, 2><<<dim3(64, 8, 1), 256, 0, stream>>>(
        s1f, om1, wm1h, wm1l, dcn1_b, Ib, 128, 128, 64, 64);

    // offset_sum(om1) (frees om1 for conv5 lumped weights)
    offsum_one<<<64, 256, 0, stream>>>(om1, 4096, outp + 393216);

    // conv5: row-lumped subpixel conv, 256->64 @128x128 -> Jb + IN/ReLU
    wsplitL_kernel<<<3200, 256, 0, stream>>>(conv5_w, wL5h, wL5l, wC5h, 64, 256);
    conv_mfma5<bf16, bf16, 3, 64, 4, 4><<<dim3(64, 8, 1), 512, 0, stream>>>(
        Ib, Fb, 128, 256, wL5h, wL5l, wC5h, conv5_b, Jb, 64, 128, 128);
    inorm_kernel<bf16><<<512, 256, 0, stream>>>(Jb, nullptr, 16384, 0);

    // conv6: 7x7, 64->3, tanh via conv_mfma3 (tiled staging, XCD-pinned, padded O=32)
    wsplit2p_kernel<<<392, 256, 0, stream>>>(conv6_w, wt6h, wt6l, 3, 32, 64, 49);
    conv_mfma3<bf16, float, 7, false, 3, false, 10, 128, 4, 8, true><<<dim3(32, 8, 1), 1024, 0, stream>>>(
        Jb, (const float*)nullptr, 64, 64, wt6h, wt6l, conv6_b, (void*)outp, 32, 128, 128);
}